// Round 3
// baseline (156.453 us; speedup 1.0000x reference)
//
#include <hip/hip_runtime.h>

#define NIVL  256
#define KINV  51.2f        // 256/5
#define KSTEP 0.01953125f  // 5/256 (exact in fp32)
#define TPW   7168
#define BCAP  256          // max edges per L-bin (avg 128)
#define NROW  11           // distinct t-rows: t00,t11,t01[3],t10[3],t12[3]
#define TSTR  40           // u-stride (pad 32->40: 80B rows -> 16B-aligned b128)
#define PREPT 455          // T-build blocks: ceil(257/4)=65 k-groups x 7 w-slices

typedef __attribute__((ext_vector_type(8))) __bf16 bf16x8;
typedef __attribute__((ext_vector_type(4))) float f32x4;
union FragU { uint4 u; bf16x8 v; };

__device__ __forceinline__ float sigmoidf_(float v) { return 1.f / (1.f + expf(-v)); }
__device__ __forceinline__ unsigned bf16r_(float x) { return (__float_as_uint(x) + 0x8000u) >> 16; }
__device__ __forceinline__ unsigned pk_(float lo, float hi) { return (bf16r_(hi) << 16) | bf16r_(lo); }

__device__ __forceinline__ f32x4 mfma_(bf16x8 a, bf16x8 b, f32x4 c) {
    return __builtin_amdgcn_mfma_f32_16x16x32_bf16(a, b, c, 0, 0, 0);
}

// ---- fat kernel: blocks 0..454 build T (257 knots, 4/block), blocks 455.. scatter ----
// Scatter bakes a 64B edge record (f, src, dst, y0, y1*I3, M-matrix) per bin slot.
__global__ __launch_bounds__(256)
void prep_kernel(const float* __restrict__ W1, const float* __restrict__ W2,
                 const float* __restrict__ elen, const int* __restrict__ esrc,
                 const int* __restrict__ edst, const float* __restrict__ ea,
                 float* __restrict__ T, int* __restrict__ cntL, int* __restrict__ cntD,
                 float* __restrict__ erec, int E)
{
    const int tid = threadIdx.x;
    if (blockIdx.x < PREPT) {
        __shared__ float hk_s[4][64];
        const int bx = blockIdx.x % 7;
        const int k0 = (blockIdx.x / 7) * 4;
        const int pw = bx * 1024 + tid * 4;
        {
            int kk = tid >> 6, c = tid & 63;
            float L = (float)(k0 + kk) * KSTEP;
            float d = 0.f;
#pragma unroll
            for (int r = 0; r < 8; ++r) {
                float dd = L - (float)r * (5.f / 7.f);
                d += expf(-dd * dd * 0.98f) * W1[r * 64 + c];
            }
            d *= 0.3535533906f;                      // 1/sqrt(8)
            hk_s[kk][c] = d * sigmoidf_(d) * 0.125f; // silu * 1/sqrt(64)
        }
        __syncthreads();
        float4 acc[4];
#pragma unroll
        for (int q = 0; q < 4; ++q) acc[q] = make_float4(0.f, 0.f, 0.f, 0.f);
        // unroll 4: keep 4 independent W2 loads (28KB stride, L2) in flight
#pragma unroll 4
        for (int c = 0; c < 64; ++c) {
            float4 w4 = *(const float4*)(W2 + (size_t)c * TPW + pw);
#pragma unroll
            for (int q = 0; q < 4; ++q) {
                float hv = hk_s[q][c];
                acc[q].x = fmaf(hv, w4.x, acc[q].x);
                acc[q].y = fmaf(hv, w4.y, acc[q].y);
                acc[q].z = fmaf(hv, w4.z, acc[q].z);
                acc[q].w = fmaf(hv, w4.w, acc[q].w);
            }
        }
#pragma unroll
        for (int q = 0; q < 4; ++q) {
            int k = k0 + q;
            if (k < 257)
                *(float4*)(T + (size_t)k * TPW + pw) = acc[q];
        }
    } else {
        const float I3 = 0.5773502692f, I5 = 0.4472135955f, S2 = 0.7071067812f;
        const float I6 = 0.4082482905f, T6 = 0.8164965809f;
        int e = (blockIdx.x - PREPT) * 256 + tid;
        if (e < E) {
            float t = elen[e] * KINV;
            int j = (int)t; j = j > 255 ? 255 : j;
            int d = edst[e];
            int pos = atomicAdd(&cntL[j], 1);
            if (pos < BCAP) {
                const float* y = ea + (size_t)e * 9;
                float y0 = y[0];
                float a = y[4], b = y[5], c = y[6], d2 = y[7], ee = y[8];
                float4 r0, r1, r2, r3;
                r0.x = t - (float)j;
                r0.y = __int_as_float(esrc[e]);
                r0.z = __int_as_float(d);
                r0.w = y0;
                r1.x = y0 * I3;
                r1.y = y[1] * I3; r1.z = y[2] * I3; r1.w = y[3] * I3;
                r2.x = (-c * I6 + ee * S2) * I5;   // M0
                r2.y = a * S2 * I5;                // M1 (=M3)
                r2.z = d2 * S2 * I5;               // M2 (=M6)
                r2.w = (-c * I6 - ee * S2) * I5;   // M4
                r3.x = b * S2 * I5;                // M5 (=M7)
                r3.y = c * T6 * I5;                // M8
                r3.z = 0.f; r3.w = 0.f;
                float4* dst = (float4*)(erec + ((size_t)j * BCAP + pos) * 16);
                dst[0] = r0; dst[1] = r1; dst[2] = r2; dst[3] = r3;
            }
            atomicAdd(&cntD[d], 1);
        }
    }
}

// ---- main fold: MFMA formulation, scatter-add epilogue ----
// Per interval j (2 blocks, halves): stage bf16 B-frags of Ta=T[j], D=T[j+1]-T[j];
// per 32-edge chunk: edge record prefetched one chunk ahead; x-row load issues
// before the barrier. t-build builds 11 bf16 t-rows/edge in LDS; 4 waves x 26
// MFMAs; epilogue scatter-adds (Ta + f*D)*scale into per-node sums (2.6MB, L2).
__global__ __launch_bounds__(256, 2)
void fold_kernel(const float* __restrict__ x, const int* __restrict__ cntL,
                 const float* __restrict__ erec, const float* __restrict__ T,
                 float* __restrict__ sums)
{
    const int j = blockIdx.x >> 1, half = blockIdx.x & 1;
    __shared__ uint4 BF[7 * 2 * 2 * 64];                       // 28672 B
    __shared__ __align__(16) unsigned short TB[2 * NROW * 16 * TSTR]; // 28160 B
    __shared__ float ECF[32];
    __shared__ int   ECE[32];
    const int tid = threadIdx.x;

    const int cnt = min(cntL[j], BCAP);
    const int nchunk = (cnt + 31) >> 5;
    const int te = tid & 31, sub = tid >> 5;     // t-build mapping

    // ---- prologue: load edge record for first chunk (overlaps BF staging) ----
    float4 er0 = {0,0,0,0}, er1 = {0,0,0,0}, er2 = {0,0,0,0}, er3 = {0,0,0,0};
    if (half < nchunk) {
        int ce = min(32, cnt - (half << 5));
        if (te < ce) {
            const float4* rp = (const float4*)(erec + ((size_t)j * BCAP + (half << 5) + te) * 16);
            er0 = rp[0]; er1 = rp[1]; er2 = rp[2]; er3 = rp[3];
        }
    }

    // ---- stage B-fragments: entry (p, wh, lane) -> Ta frag + D frag ----
    const float* Trow  = T + (size_t)j * TPW;
    const float* Trow2 = Trow + TPW;
    for (int i = tid; i < 896; i += 256) {
        int pl = i >> 7, rem = i & 127;
        int whs = rem >> 6, lane_s = rem & 63;
        int u0 = (lane_s >> 4) * 8, w = whs * 16 + (lane_s & 15);
        int basei = pl * 1024 + w;
        unsigned ta[4], dd[4];
#pragma unroll
        for (int q = 0; q < 4; ++q) {
            float a0 = Trow[basei + (u0 + 2 * q) * 32];
            float a1 = Trow[basei + (u0 + 2 * q + 1) * 32];
            float b0 = Trow2[basei + (u0 + 2 * q) * 32];
            float b1 = Trow2[basei + (u0 + 2 * q + 1) * 32];
            ta[q] = pk_(a0, a1);
            dd[q] = pk_(b0 - a0, b1 - a1);
        }
        BF[(pl * 4 + whs) * 64 + lane_s]     = make_uint4(ta[0], ta[1], ta[2], ta[3]);
        BF[(pl * 4 + 2 + whs) * 64 + lane_s] = make_uint4(dd[0], dd[1], dd[2], dd[3]);
    }

    const int wv = tid >> 6, lane = tid & 63;
    const int sg = wv >> 1, wh = wv & 1;
    const int col = lane & 15, quad = lane >> 4;
    const float A0 = 0.125f, A1 = 0.1767766953f;

    for (int ci = half; ci < nchunk; ci += 2) {
        const int base = ci << 5;
        const int cntE = min(32, cnt - base);

        // ---- x-row load for current chunk (record already in regs) ----
        const int u0 = sub * 4;
        float s4[4], vv[12];
        if (te < cntE) {
            int src = __float_as_int(er0.y);
            const float* xp = x + (size_t)src * 128;
            *(float4*)s4 = *(const float4*)(xp + u0);
            *(float4*)(vv)     = *(const float4*)(xp + 32 + 3 * u0);
            *(float4*)(vv + 4) = *(const float4*)(xp + 32 + 3 * u0 + 4);
            *(float4*)(vv + 8) = *(const float4*)(xp + 32 + 3 * u0 + 8);
        }
        // ---- prefetch next chunk's record ----
        float4 nr0 = {0,0,0,0}, nr1 = {0,0,0,0}, nr2 = {0,0,0,0}, nr3 = {0,0,0,0};
        const int cin = ci + 2;
        if (cin < nchunk) {
            int ce2 = min(32, cnt - (cin << 5));
            if (te < ce2) {
                const float4* rp = (const float4*)(erec + ((size_t)j * BCAP + (cin << 5) + te) * 16);
                nr0 = rp[0]; nr1 = rp[1]; nr2 = rp[2]; nr3 = rp[3];
            }
        }

        __syncthreads();   // BF ready (iter 0); TB/ECF/ECE free (later iters)

        // ---- t-build: thread (te, sub) computes rows for edge te, u0..u0+3 ----
        {
            const int esg = te >> 4, e16 = te & 15;
            float rv[NROW][4];
            if (te < cntE) {
                float y0 = er0.w;
                float y0i = er1.x, y1i0 = er1.y, y1i1 = er1.z, y1i2 = er1.w;
                float M0 = er2.x, M1 = er2.y, M2 = er2.z, M4 = er2.w;
                float M5 = er3.x, M8 = er3.y;
                if (sub == 0) {
                    ECF[te] = er0.x;
                    ECE[te] = __float_as_int(er0.z);   // dst node
                }
#pragma unroll
                for (int up = 0; up < 4; ++up) {
                    float s = s4[up];
                    float v0 = vv[3 * up], v1 = vv[3 * up + 1], v2 = vv[3 * up + 2];
                    rv[0][up] = s * y0;
                    rv[1][up] = v0 * y1i0 + v1 * y1i1 + v2 * y1i2;
                    rv[2][up] = s * y1i0;
                    rv[3][up] = s * y1i1;
                    rv[4][up] = s * y1i2;
                    rv[5][up] = v0 * y0i;
                    rv[6][up] = v1 * y0i;
                    rv[7][up] = v2 * y0i;
                    rv[8][up]  = v0 * M0 + v1 * M1 + v2 * M2;
                    rv[9][up]  = v0 * M1 + v1 * M4 + v2 * M5;
                    rv[10][up] = v0 * M2 + v1 * M5 + v2 * M8;
                }
            } else {
#pragma unroll
                for (int r = 0; r < NROW; ++r)
#pragma unroll
                    for (int up = 0; up < 4; ++up) rv[r][up] = 0.f;
            }
#pragma unroll
            for (int r = 0; r < NROW; ++r) {
                unsigned lo = pk_(rv[r][0], rv[r][1]);
                unsigned hi = pk_(rv[r][2], rv[r][3]);
                *(uint2*)&TB[((esg * NROW + r) * 16 + e16) * TSTR + u0] = make_uint2(lo, hi);
            }
        }
        __syncthreads();

        // ---- MFMA phase: wave (sg, wh) ----
        f32x4 cS0 = {0,0,0,0}, cS1 = {0,0,0,0}, cG0 = {0,0,0,0}, cG1 = {0,0,0,0};
        f32x4 cV[3][2];
#pragma unroll
        for (int k = 0; k < 3; ++k) { cV[k][0] = (f32x4){0,0,0,0}; cV[k][1] = (f32x4){0,0,0,0}; }

        #define LOADA(r) ({ FragU fa_; fa_.u = *(const uint4*)&TB[((sg * NROW + (r)) * 16 + col) * TSTR + quad * 8]; fa_.v; })
        #define LOADB(p, tad) ({ FragU fb_; fb_.u = BF[((p) * 4 + (tad) * 2 + wh) * 64 + lane]; fb_.v; })

        bf16x8 a0 = LOADA(0), a1 = LOADA(1);
        cS0 = mfma_(a0, LOADB(0, 0), cS0); cS0 = mfma_(a1, LOADB(1, 0), cS0);
        cS1 = mfma_(a0, LOADB(0, 1), cS1); cS1 = mfma_(a1, LOADB(1, 1), cS1);
        cG0 = mfma_(a0, LOADB(2, 0), cG0); cG0 = mfma_(a1, LOADB(3, 0), cG0);
        cG1 = mfma_(a0, LOADB(2, 1), cG1); cG1 = mfma_(a1, LOADB(3, 1), cG1);
#pragma unroll
        for (int k = 0; k < 3; ++k) {
            bf16x8 ak;
            ak = LOADA(2 + k);
            cV[k][0] = mfma_(ak, LOADB(4, 0), cV[k][0]);
            cV[k][1] = mfma_(ak, LOADB(4, 1), cV[k][1]);
            ak = LOADA(5 + k);
            cV[k][0] = mfma_(ak, LOADB(5, 0), cV[k][0]);
            cV[k][1] = mfma_(ak, LOADB(5, 1), cV[k][1]);
            ak = LOADA(8 + k);
            cV[k][0] = mfma_(ak, LOADB(6, 0), cV[k][0]);
            cV[k][1] = mfma_(ak, LOADB(6, 1), cV[k][1]);
        }

        // ---- epilogue: combine Ta + f*D, scale, scatter-add to node sums ----
        const int w = wh * 16 + col;
#pragma unroll
        for (int reg = 0; reg < 4; ++reg) {
            int e = sg * 16 + quad * 4 + reg;
            if (e < cntE) {
                float f = ECF[e];
                int dst = ECE[e];
                float* mp = sums + (size_t)dst * 160;
                unsafeAtomicAdd(mp + w,              (cS0[reg] + f * cS1[reg]) * A0);
                unsafeAtomicAdd(mp + 32 + w,         (cG0[reg] + f * cG1[reg]) * A0);
                unsafeAtomicAdd(mp + 64 + 3 * w,     (cV[0][0][reg] + f * cV[0][1][reg]) * A1);
                unsafeAtomicAdd(mp + 64 + 3 * w + 1, (cV[1][0][reg] + f * cV[1][1][reg]) * A1);
                unsafeAtomicAdd(mp + 64 + 3 * w + 2, (cV[2][0][reg] + f * cV[2][1][reg]) * A1);
            }
        }
        #undef LOADA
        #undef LOADB
        er0 = nr0; er1 = nr1; er2 = nr2; er3 = nr3;
    }
}

// ---- node epilogue: 8 nodes per block, sums already reduced ----
__global__ __launch_bounds__(256)
void node_kernel(const float* __restrict__ x, const float* __restrict__ Wss,
                 const float* __restrict__ Wsv, const float* __restrict__ sums,
                 const int* __restrict__ cntD, float* __restrict__ out, int N)
{
    __shared__ float ms[8][160];
    const int tid = threadIdx.x;
    const int n0 = blockIdx.x * 8;
    const float IM = 0.1767766953f;  // 1/sqrt(32)

    // load + divide: 8 nodes x 160 = 320 float4 tasks
#pragma unroll
    for (int it = 0; it < 2; ++it) {
        int task = tid + it * 256;
        if (task < 320) {
            int nl = task / 40, q = task - nl * 40;
            int n = n0 + nl;
            if (n < N) {
                float inv = 1.f / fmaxf((float)cntD[n], 1.f);
                float4 v = *(const float4*)(sums + (size_t)n * 160 + q * 4);
                ms[nl][q * 4 + 0] = v.x * inv;
                ms[nl][q * 4 + 1] = v.y * inv;
                ms[nl][q * 4 + 2] = v.z * inv;
                ms[nl][q * 4 + 3] = v.w * inv;
            }
        }
    }
    __syncthreads();

#pragma unroll
    for (int it = 0; it < 2; ++it) {
        int task = tid + it * 256;
        int nl = task >> 6, col = task & 63;
        int n = n0 + nl;
        if (n >= N) continue;
        const float* m  = ms[nl];
        const float* xp = x + (size_t)n * 128;
        if (col < 32) {
            int w = col;
            float mval = m[w];
            float gs = mval * sigmoidf_(mval);
            float dot = 0.f;
#pragma unroll 4
            for (int u = 0; u < 32; ++u) dot += xp[u] * Wss[u * 32 + w];
            float hs = gs + dot * IM;
            out[(size_t)n * 64 + w] = sqrtf(hs * hs + 1e-12f);
        } else {
            int w = col - 32;
            float gate = sigmoidf_(m[32 + w]);
            float g0 = m[64 + 3 * w + 0] * gate;
            float g1 = m[64 + 3 * w + 1] * gate;
            float g2 = m[64 + 3 * w + 2] * gate;
            float d0 = 0.f, d1 = 0.f, d2 = 0.f;
#pragma unroll 4
            for (int u = 0; u < 32; ++u) {
                float wv = Wsv[u * 32 + w];
                d0 += xp[32 + 3 * u + 0] * wv;
                d1 += xp[32 + 3 * u + 1] * wv;
                d2 += xp[32 + 3 * u + 2] * wv;
            }
            float h0 = g0 + d0 * IM, h1 = g1 + d1 * IM, h2 = g2 + d2 * IM;
            out[(size_t)n * 64 + 32 + w] = sqrtf(h0 * h0 + h1 * h1 + h2 * h2 + 1e-12f);
        }
    }
}

extern "C" void kernel_launch(void* const* d_in, const int* in_sizes, int n_in,
                              void* d_out, int out_size, void* d_ws, size_t ws_size,
                              hipStream_t stream)
{
    const float* x    = (const float*)d_in[0];
    const float* ea   = (const float*)d_in[1];
    const float* elen = (const float*)d_in[2];
    const int*   esrc = (const int*)d_in[3];
    const int*   edst = (const int*)d_in[4];
    const float* W1   = (const float*)d_in[5];
    const float* W2   = (const float*)d_in[6];
    const float* Wss  = (const float*)d_in[7];
    const float* Wsv  = (const float*)d_in[8];
    float* out = (float*)d_out;

    const int N = in_sizes[0] / 128;   // 4096
    const int E = in_sizes[2];         // 32768

    float* T      = (float*)d_ws;                       // 257*TPW floats (7.4 MB)
    float* erec   = T + (size_t)257 * TPW;              // 256*BCAP*16 floats (4 MB)
    float* sums   = erec + (size_t)256 * BCAP * 16;     // N*160 floats (2.6 MB)
    int*   cntL   = (int*)(sums + (size_t)N * 160);     // 256
    int*   cntD   = cntL + 256;                         // N (4096)

    // zero sums + cntL + cntD in one contiguous memset
    hipMemsetAsync(sums, 0, ((size_t)N * 160 + 256 + N) * sizeof(float), stream);

    prep_kernel<<<PREPT + (E + 255) / 256, 256, 0, stream>>>(W1, W2, elen, esrc, edst, ea, T, cntL, cntD, erec, E);
    fold_kernel<<<NIVL * 2, 256, 0, stream>>>(x, cntL, erec, T, sums);
    node_kernel<<<(N + 7) / 8, 256, 0, stream>>>(x, Wss, Wsv, sums, cntD, out, N);
}

// Round 4
// 149.787 us; speedup vs baseline: 1.0445x; 1.0445x over previous
//
#include <hip/hip_runtime.h>

#define NIVL  256
#define KINV  51.2f        // 256/5
#define KSTEP 0.01953125f  // 5/256 (exact in fp32)
#define TPW   7168
#define BCAP  256          // max edges per L-bin (avg 128)
#define DCAP  64           // max edges per dst node (avg 8)
#define NROW  11           // distinct t-rows: t00,t11,t01[3],t10[3],t12[3]
#define TSTR  40           // u-stride (pad 32->40: 80B rows -> 16B-aligned b128)
#define PREPT 455          // T-build blocks: ceil(257/4)=65 k-groups x 7 w-slices

typedef __attribute__((ext_vector_type(8))) __bf16 bf16x8;
typedef __attribute__((ext_vector_type(4))) float f32x4;
union FragU { uint4 u; bf16x8 v; };

__device__ __forceinline__ float sigmoidf_(float v) { return 1.f / (1.f + expf(-v)); }
__device__ __forceinline__ unsigned bf16r_(float x) { return (__float_as_uint(x) + 0x8000u) >> 16; }
__device__ __forceinline__ unsigned pk_(float lo, float hi) { return (bf16r_(hi) << 16) | bf16r_(lo); }

__device__ __forceinline__ f32x4 mfma_(bf16x8 a, bf16x8 b, f32x4 c) {
    return __builtin_amdgcn_mfma_f32_16x16x32_bf16(a, b, c, 0, 0, 0);
}

// ---- fat kernel: blocks 0..454 build T (257 knots, 4/block), blocks 455.. scatter ----
// Scatter bakes a 64B edge record (EREC) so fold never chases esrc/ea/elen.
__global__ __launch_bounds__(256)
void prep_kernel(const float* __restrict__ W1, const float* __restrict__ W2,
                 const float* __restrict__ elen, const int* __restrict__ esrc,
                 const int* __restrict__ edst, const float* __restrict__ ea,
                 float* __restrict__ T, int* __restrict__ cntL, int* __restrict__ cntD,
                 float* __restrict__ erec, int* __restrict__ sortedD, int E)
{
    const int tid = threadIdx.x;
    if (blockIdx.x < PREPT) {
        __shared__ float hk_s[4][64];
        const int bx = blockIdx.x % 7;
        const int k0 = (blockIdx.x / 7) * 4;
        const int pw = bx * 1024 + tid * 4;
        {
            int kk = tid >> 6, c = tid & 63;
            float L = (float)(k0 + kk) * KSTEP;
            float d = 0.f;
#pragma unroll
            for (int r = 0; r < 8; ++r) {
                float dd = L - (float)r * (5.f / 7.f);
                d += expf(-dd * dd * 0.98f) * W1[r * 64 + c];
            }
            d *= 0.3535533906f;                      // 1/sqrt(8)
            hk_s[kk][c] = d * sigmoidf_(d) * 0.125f; // silu * 1/sqrt(64)
        }
        __syncthreads();
        float4 acc[4];
#pragma unroll
        for (int q = 0; q < 4; ++q) acc[q] = make_float4(0.f, 0.f, 0.f, 0.f);
        // unroll 4: keep 4 independent W2 loads (28KB stride, L2) in flight
#pragma unroll 4
        for (int c = 0; c < 64; ++c) {
            float4 w4 = *(const float4*)(W2 + (size_t)c * TPW + pw);
#pragma unroll
            for (int q = 0; q < 4; ++q) {
                float hv = hk_s[q][c];
                acc[q].x = fmaf(hv, w4.x, acc[q].x);
                acc[q].y = fmaf(hv, w4.y, acc[q].y);
                acc[q].z = fmaf(hv, w4.z, acc[q].z);
                acc[q].w = fmaf(hv, w4.w, acc[q].w);
            }
        }
#pragma unroll
        for (int q = 0; q < 4; ++q) {
            int k = k0 + q;
            if (k < 257)
                *(float4*)(T + (size_t)k * TPW + pw) = acc[q];
        }
    } else {
        const float I3 = 0.5773502692f, I5 = 0.4472135955f, S2 = 0.7071067812f;
        const float I6 = 0.4082482905f, T6 = 0.8164965809f;
        int e = (blockIdx.x - PREPT) * 256 + tid;
        if (e < E) {
            float t = elen[e] * KINV;
            int j = (int)t; j = j > 255 ? 255 : j;
            int pos = atomicAdd(&cntL[j], 1);
            if (pos < BCAP) {
                const float* y = ea + (size_t)e * 9;
                float y0 = y[0];
                float a = y[4], b = y[5], c = y[6], d2 = y[7], ee = y[8];
                float4 r0, r1, r2, r3;
                r0.x = t - (float)j;
                r0.y = __int_as_float(esrc[e]);
                r0.z = __int_as_float(e);
                r0.w = y0;
                r1.x = y0 * I3;
                r1.y = y[1] * I3; r1.z = y[2] * I3; r1.w = y[3] * I3;
                r2.x = (-c * I6 + ee * S2) * I5;   // M0
                r2.y = a * S2 * I5;                // M1 (=M3)
                r2.z = d2 * S2 * I5;               // M2 (=M6)
                r2.w = (-c * I6 - ee * S2) * I5;   // M4
                r3.x = b * S2 * I5;                // M5 (=M7)
                r3.y = c * T6 * I5;                // M8
                r3.z = 0.f; r3.w = 0.f;
                float4* dst = (float4*)(erec + ((size_t)j * BCAP + pos) * 16);
                dst[0] = r0; dst[1] = r1; dst[2] = r2; dst[3] = r3;
            }
            int d = edst[e];
            int pd = atomicAdd(&cntD[d], 1);
            if (pd < DCAP) sortedD[d * DCAP + pd] = e;
        }
    }
}

// ---- main fold: MFMA formulation, B-fragments in registers ----
// 4 blocks per interval (quarter-strided chunks). Per block: each lane loads its
// own 14 B-fragments (7 paths x {Ta, D=T[j+1]-T[j]}) global->reg once (56 VGPR,
// loop-invariant) -- no BF LDS, no staging barrier. LDS = TB only (28.5KB) ->
// 3+ blocks/CU. Per 32-edge chunk: erec prefetched one chunk ahead; x-row load
// issues before the barrier; t-build 11 bf16 rows/edge in LDS; 26 MFMAs/wave.
__global__ __launch_bounds__(256, 3)
void fold_kernel(const float* __restrict__ x, const int* __restrict__ cntL,
                 const float* __restrict__ erec, const float* __restrict__ T,
                 float* __restrict__ msg)
{
    const int j = blockIdx.x >> 2, qtr = blockIdx.x & 3;
    __shared__ __align__(16) unsigned short TB[2 * NROW * 16 * TSTR]; // 28160 B
    __shared__ float ECF[32];
    __shared__ int   ECE[32];
    const int tid = threadIdx.x;

    const int cnt = min(cntL[j], BCAP);
    const int nchunk = (cnt + 31) >> 5;
    const int te = tid & 31, sub = tid >> 5;     // t-build mapping
    const int wv = tid >> 6, lane = tid & 63;
    const int sg = wv >> 1, wh = wv & 1;
    const int col = lane & 15, quad = lane >> 4;

    // ---- prologue: load edge record for first chunk (overlaps B-frag loads) ----
    float4 er0 = {0,0,0,0}, er1 = {0,0,0,0}, er2 = {0,0,0,0}, er3 = {0,0,0,0};
    if (qtr < nchunk) {
        int ce = min(32, cnt - (qtr << 5));
        if (te < ce) {
            const float4* rp = (const float4*)(erec + ((size_t)j * BCAP + (qtr << 5) + te) * 16);
            er0 = rp[0]; er1 = rp[1]; er2 = rp[2]; er3 = rp[3];
        }
    }

    // ---- B-fragments direct to registers (loop-invariant) ----
    bf16x8 Bt[7][2];
    {
        const float* Trow  = T + (size_t)j * TPW;
        const float* Trow2 = Trow + TPW;
        const int u0 = quad * 8, w = wh * 16 + col;
#pragma unroll
        for (int pl = 0; pl < 7; ++pl) {
            unsigned ta[4], dd[4];
#pragma unroll
            for (int q = 0; q < 4; ++q) {
                float a0 = Trow[pl * 1024 + (u0 + 2 * q) * 32 + w];
                float a1 = Trow[pl * 1024 + (u0 + 2 * q + 1) * 32 + w];
                float b0 = Trow2[pl * 1024 + (u0 + 2 * q) * 32 + w];
                float b1 = Trow2[pl * 1024 + (u0 + 2 * q + 1) * 32 + w];
                ta[q] = pk_(a0, a1);
                dd[q] = pk_(b0 - a0, b1 - a1);
            }
            FragU fa; fa.u = make_uint4(ta[0], ta[1], ta[2], ta[3]); Bt[pl][0] = fa.v;
            FragU fd; fd.u = make_uint4(dd[0], dd[1], dd[2], dd[3]); Bt[pl][1] = fd.v;
        }
    }

    const float A0 = 0.125f, A1 = 0.1767766953f;

    for (int ci = qtr; ci < nchunk; ci += 4) {
        const int base = ci << 5;
        const int cntE = min(32, cnt - base);

        // ---- x-row load for current chunk (record already in regs) ----
        const int u0 = sub * 4;
        float s4[4], vv[12];
        if (te < cntE) {
            int src = __float_as_int(er0.y);
            const float* xp = x + (size_t)src * 128;
            *(float4*)s4 = *(const float4*)(xp + u0);
            *(float4*)(vv)     = *(const float4*)(xp + 32 + 3 * u0);
            *(float4*)(vv + 4) = *(const float4*)(xp + 32 + 3 * u0 + 4);
            *(float4*)(vv + 8) = *(const float4*)(xp + 32 + 3 * u0 + 8);
        }
        // ---- prefetch next chunk's record ----
        float4 nr0 = {0,0,0,0}, nr1 = {0,0,0,0}, nr2 = {0,0,0,0}, nr3 = {0,0,0,0};
        const int cin = ci + 4;
        if (cin < nchunk) {
            int ce2 = min(32, cnt - (cin << 5));
            if (te < ce2) {
                const float4* rp = (const float4*)(erec + ((size_t)j * BCAP + (cin << 5) + te) * 16);
                nr0 = rp[0]; nr1 = rp[1]; nr2 = rp[2]; nr3 = rp[3];
            }
        }

        __syncthreads();   // TB/ECF/ECE free (prior iter consumed)

        // ---- t-build: thread (te, sub) computes rows for edge te, u0..u0+3 ----
        {
            const int esg = te >> 4, e16 = te & 15;
            float rv[NROW][4];
            if (te < cntE) {
                float y0 = er0.w;
                float y0i = er1.x, y1i0 = er1.y, y1i1 = er1.z, y1i2 = er1.w;
                float M0 = er2.x, M1 = er2.y, M2 = er2.z, M4 = er2.w;
                float M5 = er3.x, M8 = er3.y;
                if (sub == 0) {
                    ECF[te] = er0.x;
                    ECE[te] = __float_as_int(er0.z);   // edge id
                }
#pragma unroll
                for (int up = 0; up < 4; ++up) {
                    float s = s4[up];
                    float v0 = vv[3 * up], v1 = vv[3 * up + 1], v2 = vv[3 * up + 2];
                    rv[0][up] = s * y0;
                    rv[1][up] = v0 * y1i0 + v1 * y1i1 + v2 * y1i2;
                    rv[2][up] = s * y1i0;
                    rv[3][up] = s * y1i1;
                    rv[4][up] = s * y1i2;
                    rv[5][up] = v0 * y0i;
                    rv[6][up] = v1 * y0i;
                    rv[7][up] = v2 * y0i;
                    rv[8][up]  = v0 * M0 + v1 * M1 + v2 * M2;
                    rv[9][up]  = v0 * M1 + v1 * M4 + v2 * M5;
                    rv[10][up] = v0 * M2 + v1 * M5 + v2 * M8;
                }
            } else {
#pragma unroll
                for (int r = 0; r < NROW; ++r)
#pragma unroll
                    for (int up = 0; up < 4; ++up) rv[r][up] = 0.f;
            }
#pragma unroll
            for (int r = 0; r < NROW; ++r) {
                unsigned lo = pk_(rv[r][0], rv[r][1]);
                unsigned hi = pk_(rv[r][2], rv[r][3]);
                *(uint2*)&TB[((esg * NROW + r) * 16 + e16) * TSTR + u0] = make_uint2(lo, hi);
            }
        }
        __syncthreads();

        // ---- MFMA phase: wave (sg, wh) ----
        f32x4 cS0 = {0,0,0,0}, cS1 = {0,0,0,0}, cG0 = {0,0,0,0}, cG1 = {0,0,0,0};
        f32x4 cV[3][2];
#pragma unroll
        for (int k = 0; k < 3; ++k) { cV[k][0] = (f32x4){0,0,0,0}; cV[k][1] = (f32x4){0,0,0,0}; }

        #define LOADA(r) ({ FragU fa_; fa_.u = *(const uint4*)&TB[((sg * NROW + (r)) * 16 + col) * TSTR + quad * 8]; fa_.v; })

        bf16x8 a0 = LOADA(0), a1 = LOADA(1);
        cS0 = mfma_(a0, Bt[0][0], cS0); cS0 = mfma_(a1, Bt[1][0], cS0);
        cS1 = mfma_(a0, Bt[0][1], cS1); cS1 = mfma_(a1, Bt[1][1], cS1);
        cG0 = mfma_(a0, Bt[2][0], cG0); cG0 = mfma_(a1, Bt[3][0], cG0);
        cG1 = mfma_(a0, Bt[2][1], cG1); cG1 = mfma_(a1, Bt[3][1], cG1);
#pragma unroll
        for (int k = 0; k < 3; ++k) {
            bf16x8 ak;
            ak = LOADA(2 + k);
            cV[k][0] = mfma_(ak, Bt[4][0], cV[k][0]);
            cV[k][1] = mfma_(ak, Bt[4][1], cV[k][1]);
            ak = LOADA(5 + k);
            cV[k][0] = mfma_(ak, Bt[5][0], cV[k][0]);
            cV[k][1] = mfma_(ak, Bt[5][1], cV[k][1]);
            ak = LOADA(8 + k);
            cV[k][0] = mfma_(ak, Bt[6][0], cV[k][0]);
            cV[k][1] = mfma_(ak, Bt[6][1], cV[k][1]);
        }

        // ---- epilogue: combine Ta + f*D, scale, store ----
        const int w = wh * 16 + col;
#pragma unroll
        for (int reg = 0; reg < 4; ++reg) {
            int e = sg * 16 + quad * 4 + reg;
            if (e < cntE) {
                float f = ECF[e];
                int eid = ECE[e];
                float* mp = msg + (size_t)eid * 160;
                mp[w]            = (cS0[reg] + f * cS1[reg]) * A0;
                mp[32 + w]       = (cG0[reg] + f * cG1[reg]) * A0;
                mp[64 + 3 * w]     = (cV[0][0][reg] + f * cV[0][1][reg]) * A1;
                mp[64 + 3 * w + 1] = (cV[1][0][reg] + f * cV[1][1][reg]) * A1;
                mp[64 + 3 * w + 2] = (cV[2][0][reg] + f * cV[2][1][reg]) * A1;
            }
        }
        #undef LOADA
        er0 = nr0; er1 = nr1; er2 = nr2; er3 = nr3;
    }
}

// ---- fused gather + node epilogue: 8 nodes per block ----
__global__ __launch_bounds__(256)
void node_kernel(const float* __restrict__ x, const float* __restrict__ Wss,
                 const float* __restrict__ Wsv, const float* __restrict__ msg,
                 const int* __restrict__ sortedD, const int* __restrict__ cntD,
                 float* __restrict__ out, int N)
{
    __shared__ float ms[8][160];
    const int tid = threadIdx.x;
    const int n0 = blockIdx.x * 8;
    const float IM = 0.1767766953f;  // 1/sqrt(32)

#pragma unroll
    for (int it = 0; it < 5; ++it) {
        int task = tid + it * 256;
        int nl = task / 160;
        int c = task - nl * 160;
        int n = n0 + nl;
        if (n < N) {
            int cd = cntD[n];
            int cc = cd < DCAP ? cd : DCAP;
            const int* sp = sortedD + n * DCAP;
            float s = 0.f;
            // 8-wide MLP: preload indices (int4), issue 8 predicated msg loads
            for (int i0 = 0; i0 < cc; i0 += 8) {
                int4 ia = *(const int4*)(sp + i0);
                int4 ib = *(const int4*)(sp + i0 + 4);
                int id[8] = { ia.x, ia.y, ia.z, ia.w, ib.x, ib.y, ib.z, ib.w };
                float p[8];
#pragma unroll
                for (int k = 0; k < 8; ++k)
                    p[k] = (i0 + k < cc) ? msg[(size_t)id[k] * 160 + c] : 0.f;
#pragma unroll
                for (int k = 0; k < 8; ++k) s += p[k];
            }
            ms[nl][c] = s / fmaxf((float)cd, 1.f);
        }
    }
    __syncthreads();

#pragma unroll
    for (int it = 0; it < 2; ++it) {
        int task = tid + it * 256;
        int nl = task >> 6, col = task & 63;
        int n = n0 + nl;
        if (n >= N) continue;
        const float* m  = ms[nl];
        const float* xp = x + (size_t)n * 128;
        if (col < 32) {
            int w = col;
            float mval = m[w];
            float gs = mval * sigmoidf_(mval);
            float dot = 0.f;
#pragma unroll 4
            for (int u = 0; u < 32; ++u) dot += xp[u] * Wss[u * 32 + w];
            float hs = gs + dot * IM;
            out[(size_t)n * 64 + w] = sqrtf(hs * hs + 1e-12f);
        } else {
            int w = col - 32;
            float gate = sigmoidf_(m[32 + w]);
            float g0 = m[64 + 3 * w + 0] * gate;
            float g1 = m[64 + 3 * w + 1] * gate;
            float g2 = m[64 + 3 * w + 2] * gate;
            float d0 = 0.f, d1 = 0.f, d2 = 0.f;
#pragma unroll 4
            for (int u = 0; u < 32; ++u) {
                float wv = Wsv[u * 32 + w];
                d0 += xp[32 + 3 * u + 0] * wv;
                d1 += xp[32 + 3 * u + 1] * wv;
                d2 += xp[32 + 3 * u + 2] * wv;
            }
            float h0 = g0 + d0 * IM, h1 = g1 + d1 * IM, h2 = g2 + d2 * IM;
            out[(size_t)n * 64 + 32 + w] = sqrtf(h0 * h0 + h1 * h1 + h2 * h2 + 1e-12f);
        }
    }
}

extern "C" void kernel_launch(void* const* d_in, const int* in_sizes, int n_in,
                              void* d_out, int out_size, void* d_ws, size_t ws_size,
                              hipStream_t stream)
{
    const float* x    = (const float*)d_in[0];
    const float* ea   = (const float*)d_in[1];
    const float* elen = (const float*)d_in[2];
    const int*   esrc = (const int*)d_in[3];
    const int*   edst = (const int*)d_in[4];
    const float* W1   = (const float*)d_in[5];
    const float* W2   = (const float*)d_in[6];
    const float* Wss  = (const float*)d_in[7];
    const float* Wsv  = (const float*)d_in[8];
    float* out = (float*)d_out;

    const int N = in_sizes[0] / 128;   // 4096
    const int E = in_sizes[2];         // 32768

    float* T      = (float*)d_ws;                       // 257*TPW floats (7.4 MB)
    float* msg    = T + (size_t)257 * TPW;              // E*160 floats (21 MB)
    float* erec   = msg + (size_t)E * 160;              // 256*BCAP*16 floats (4 MB)
    int*   cntL   = (int*)(erec + (size_t)256 * BCAP * 16); // 256
    int*   cntD   = cntL + 256;                         // N (4096)
    int*   sortedD= cntD + N;                           // N*DCAP

    hipMemsetAsync(cntL, 0, (size_t)(256 + N) * sizeof(int), stream);

    prep_kernel<<<PREPT + (E + 255) / 256, 256, 0, stream>>>(W1, W2, elen, esrc, edst, ea, T, cntL, cntD, erec, sortedD, E);
    fold_kernel<<<NIVL * 4, 256, 0, stream>>>(x, cntL, erec, T, msg);
    node_kernel<<<(N + 7) / 8, 256, 0, stream>>>(x, Wss, Wsv, msg, sortedD, cntD, out, N);
}

// Round 5
// 149.029 us; speedup vs baseline: 1.0498x; 1.0051x over previous
//
#include <hip/hip_runtime.h>

#define NIVL  256
#define KINV  51.2f        // 256/5
#define KSTEP 0.01953125f  // 5/256 (exact in fp32)
#define TPW   7168
#define BCAP  256          // max edges per L-bin (avg 128)
#define DCAP  64           // max edges per dst node (avg 8)
#define NROW  11           // distinct t-rows: t00,t11,t01[3],t10[3],t12[3]
#define TSTR  40           // u-stride (pad 32->40: 80B rows -> 16B-aligned b128)
#define PREPT 455          // T-build blocks: ceil(257/4)=65 k-groups x 7 w-slices

typedef __attribute__((ext_vector_type(8))) __bf16 bf16x8;
typedef __attribute__((ext_vector_type(4))) float f32x4;
union FragU { uint4 u; bf16x8 v; };

__device__ __forceinline__ float sigmoidf_(float v) { return 1.f / (1.f + expf(-v)); }
__device__ __forceinline__ unsigned bf16r_(float x) { return (__float_as_uint(x) + 0x8000u) >> 16; }
__device__ __forceinline__ unsigned pk_(float lo, float hi) { return (bf16r_(hi) << 16) | bf16r_(lo); }

__device__ __forceinline__ f32x4 mfma_(bf16x8 a, bf16x8 b, f32x4 c) {
    return __builtin_amdgcn_mfma_f32_16x16x32_bf16(a, b, c, 0, 0, 0);
}

// ---- fat kernel: blocks 0..454 build T (257 knots, 4/block), blocks 455.. scatter ----
// Scatter bakes a 64B edge record (EREC) so fold never chases esrc/ea/elen.
__global__ __launch_bounds__(256)
void prep_kernel(const float* __restrict__ W1, const float* __restrict__ W2,
                 const float* __restrict__ elen, const int* __restrict__ esrc,
                 const int* __restrict__ edst, const float* __restrict__ ea,
                 float* __restrict__ T, int* __restrict__ cntL, int* __restrict__ cntD,
                 float* __restrict__ erec, int* __restrict__ sortedD, int E)
{
    const int tid = threadIdx.x;
    if (blockIdx.x < PREPT) {
        __shared__ float hk_s[4][64];
        const int bx = blockIdx.x % 7;
        const int k0 = (blockIdx.x / 7) * 4;
        const int pw = bx * 1024 + tid * 4;
        {
            int kk = tid >> 6, c = tid & 63;
            float L = (float)(k0 + kk) * KSTEP;
            float d = 0.f;
#pragma unroll
            for (int r = 0; r < 8; ++r) {
                float dd = L - (float)r * (5.f / 7.f);
                d += expf(-dd * dd * 0.98f) * W1[r * 64 + c];
            }
            d *= 0.3535533906f;                      // 1/sqrt(8)
            hk_s[kk][c] = d * sigmoidf_(d) * 0.125f; // silu * 1/sqrt(64)
        }
        __syncthreads();
        float4 acc[4];
#pragma unroll
        for (int q = 0; q < 4; ++q) acc[q] = make_float4(0.f, 0.f, 0.f, 0.f);
        // unroll 4: keep 4 independent W2 loads (28KB stride, L2) in flight
#pragma unroll 4
        for (int c = 0; c < 64; ++c) {
            float4 w4 = *(const float4*)(W2 + (size_t)c * TPW + pw);
#pragma unroll
            for (int q = 0; q < 4; ++q) {
                float hv = hk_s[q][c];
                acc[q].x = fmaf(hv, w4.x, acc[q].x);
                acc[q].y = fmaf(hv, w4.y, acc[q].y);
                acc[q].z = fmaf(hv, w4.z, acc[q].z);
                acc[q].w = fmaf(hv, w4.w, acc[q].w);
            }
        }
#pragma unroll
        for (int q = 0; q < 4; ++q) {
            int k = k0 + q;
            if (k < 257)
                *(float4*)(T + (size_t)k * TPW + pw) = acc[q];
        }
    } else {
        const float I3 = 0.5773502692f, I5 = 0.4472135955f, S2 = 0.7071067812f;
        const float I6 = 0.4082482905f, T6 = 0.8164965809f;
        int e = (blockIdx.x - PREPT) * 256 + tid;
        if (e < E) {
            float t = elen[e] * KINV;
            int j = (int)t; j = j > 255 ? 255 : j;
            int pos = atomicAdd(&cntL[j], 1);
            if (pos < BCAP) {
                const float* y = ea + (size_t)e * 9;
                float y0 = y[0];
                float a = y[4], b = y[5], c = y[6], d2 = y[7], ee = y[8];
                float4 r0, r1, r2, r3;
                r0.x = t - (float)j;
                r0.y = __int_as_float(esrc[e]);
                r0.z = __int_as_float(e);
                r0.w = y0;
                r1.x = y0 * I3;
                r1.y = y[1] * I3; r1.z = y[2] * I3; r1.w = y[3] * I3;
                r2.x = (-c * I6 + ee * S2) * I5;   // M0
                r2.y = a * S2 * I5;                // M1 (=M3)
                r2.z = d2 * S2 * I5;               // M2 (=M6)
                r2.w = (-c * I6 - ee * S2) * I5;   // M4
                r3.x = b * S2 * I5;                // M5 (=M7)
                r3.y = c * T6 * I5;                // M8
                r3.z = 0.f; r3.w = 0.f;
                float4* dst = (float4*)(erec + ((size_t)j * BCAP + pos) * 16);
                dst[0] = r0; dst[1] = r1; dst[2] = r2; dst[3] = r3;
            }
            int d = edst[e];
            int pd = atomicAdd(&cntD[d], 1);
            if (pd < DCAP) sortedD[d * DCAP + pd] = e;
        }
    }
}

// ---- pack kernel: T -> per-lane bf16 fragment layout, once per interval ----
// Bpk[(j*28 + pl*4 + tad*2 + wh)*64 + lane] (uint4). Replicates the exact
// staging arithmetic so fold consumes identical bits. Strided scalar T reads
// happen 256 blocks' worth total here instead of per fold block.
__global__ __launch_bounds__(256)
void pack_kernel(const float* __restrict__ T, uint4* __restrict__ Bpk)
{
    const int j = blockIdx.x;
    const int tid = threadIdx.x;
    const float* Trow  = T + (size_t)j * TPW;
    const float* Trow2 = Trow + TPW;
    uint4* bp = Bpk + (size_t)j * 28 * 64;
    for (int i = tid; i < 896; i += 256) {
        int pl = i >> 7, rem = i & 127;
        int whs = rem >> 6, lane_s = rem & 63;
        int u0 = (lane_s >> 4) * 8, w = whs * 16 + (lane_s & 15);
        int basei = pl * 1024 + w;
        unsigned ta[4], dd[4];
#pragma unroll
        for (int q = 0; q < 4; ++q) {
            float a0 = Trow[basei + (u0 + 2 * q) * 32];
            float a1 = Trow[basei + (u0 + 2 * q + 1) * 32];
            float b0 = Trow2[basei + (u0 + 2 * q) * 32];
            float b1 = Trow2[basei + (u0 + 2 * q + 1) * 32];
            ta[q] = pk_(a0, a1);
            dd[q] = pk_(b0 - a0, b1 - a1);
        }
        bp[(pl * 4 + whs) * 64 + lane_s]     = make_uint4(ta[0], ta[1], ta[2], ta[3]);
        bp[(pl * 4 + 2 + whs) * 64 + lane_s] = make_uint4(dd[0], dd[1], dd[2], dd[3]);
    }
}

// ---- main fold: MFMA formulation, B-fragments from packed global ----
// 4 blocks per interval (quarter-strided chunks). Prologue: each lane does 14
// coalesced b128 loads of its own fragments (no BF LDS, no staging barriers).
// LDS = TB only (28.4KB); __launch_bounds__(256,3) -> 12 waves/CU. Per chunk:
// erec prefetched one ahead; x-row load before barrier; t-build 11 rows/edge;
// 26 MFMAs/wave; epilogue Ta + f*D -> msg.
__global__ __launch_bounds__(256, 3)
void fold_kernel(const float* __restrict__ x, const int* __restrict__ cntL,
                 const float* __restrict__ erec, const uint4* __restrict__ Bpk,
                 float* __restrict__ msg)
{
    const int j = blockIdx.x >> 2, qtr = blockIdx.x & 3;
    __shared__ __align__(16) unsigned short TB[2 * NROW * 16 * TSTR]; // 28160 B
    __shared__ float ECF[32];
    __shared__ int   ECE[32];
    const int tid = threadIdx.x;

    const int cnt = min(cntL[j], BCAP);
    const int nchunk = (cnt + 31) >> 5;
    const int te = tid & 31, sub = tid >> 5;     // t-build mapping
    const int wv = tid >> 6, lane = tid & 63;
    const int sg = wv >> 1, wh = wv & 1;
    const int col = lane & 15, quad = lane >> 4;

    // ---- prologue: load edge record for first chunk (overlaps B-frag loads) ----
    float4 er0 = {0,0,0,0}, er1 = {0,0,0,0}, er2 = {0,0,0,0}, er3 = {0,0,0,0};
    if (qtr < nchunk) {
        int ce = min(32, cnt - (qtr << 5));
        if (te < ce) {
            const float4* rp = (const float4*)(erec + ((size_t)j * BCAP + (qtr << 5) + te) * 16);
            er0 = rp[0]; er1 = rp[1]; er2 = rp[2]; er3 = rp[3];
        }
    }

    // ---- B-fragments: 14 coalesced b128 loads (loop-invariant) ----
    bf16x8 Bt[7][2];
    {
        const uint4* bp = Bpk + (size_t)j * 28 * 64 + lane;
#pragma unroll
        for (int pl = 0; pl < 7; ++pl) {
            FragU fa; fa.u = bp[(pl * 4 + wh) * 64];     Bt[pl][0] = fa.v;
            FragU fd; fd.u = bp[(pl * 4 + 2 + wh) * 64]; Bt[pl][1] = fd.v;
        }
    }

    const float A0 = 0.125f, A1 = 0.1767766953f;

    for (int ci = qtr; ci < nchunk; ci += 4) {
        const int base = ci << 5;
        const int cntE = min(32, cnt - base);

        // ---- x-row load for current chunk (record already in regs) ----
        const int u0 = sub * 4;
        float s4[4], vv[12];
        if (te < cntE) {
            int src = __float_as_int(er0.y);
            const float* xp = x + (size_t)src * 128;
            *(float4*)s4 = *(const float4*)(xp + u0);
            *(float4*)(vv)     = *(const float4*)(xp + 32 + 3 * u0);
            *(float4*)(vv + 4) = *(const float4*)(xp + 32 + 3 * u0 + 4);
            *(float4*)(vv + 8) = *(const float4*)(xp + 32 + 3 * u0 + 8);
        }
        // ---- prefetch next chunk's record ----
        float4 nr0 = {0,0,0,0}, nr1 = {0,0,0,0}, nr2 = {0,0,0,0}, nr3 = {0,0,0,0};
        const int cin = ci + 4;
        if (cin < nchunk) {
            int ce2 = min(32, cnt - (cin << 5));
            if (te < ce2) {
                const float4* rp = (const float4*)(erec + ((size_t)j * BCAP + (cin << 5) + te) * 16);
                nr0 = rp[0]; nr1 = rp[1]; nr2 = rp[2]; nr3 = rp[3];
            }
        }

        __syncthreads();   // TB/ECF/ECE free (prior iter consumed)

        // ---- t-build: thread (te, sub) computes rows for edge te, u0..u0+3 ----
        {
            const int esg = te >> 4, e16 = te & 15;
            float rv[NROW][4];
            if (te < cntE) {
                float y0 = er0.w;
                float y0i = er1.x, y1i0 = er1.y, y1i1 = er1.z, y1i2 = er1.w;
                float M0 = er2.x, M1 = er2.y, M2 = er2.z, M4 = er2.w;
                float M5 = er3.x, M8 = er3.y;
                if (sub == 0) {
                    ECF[te] = er0.x;
                    ECE[te] = __float_as_int(er0.z);   // edge id
                }
#pragma unroll
                for (int up = 0; up < 4; ++up) {
                    float s = s4[up];
                    float v0 = vv[3 * up], v1 = vv[3 * up + 1], v2 = vv[3 * up + 2];
                    rv[0][up] = s * y0;
                    rv[1][up] = v0 * y1i0 + v1 * y1i1 + v2 * y1i2;
                    rv[2][up] = s * y1i0;
                    rv[3][up] = s * y1i1;
                    rv[4][up] = s * y1i2;
                    rv[5][up] = v0 * y0i;
                    rv[6][up] = v1 * y0i;
                    rv[7][up] = v2 * y0i;
                    rv[8][up]  = v0 * M0 + v1 * M1 + v2 * M2;
                    rv[9][up]  = v0 * M1 + v1 * M4 + v2 * M5;
                    rv[10][up] = v0 * M2 + v1 * M5 + v2 * M8;
                }
            } else {
#pragma unroll
                for (int r = 0; r < NROW; ++r)
#pragma unroll
                    for (int up = 0; up < 4; ++up) rv[r][up] = 0.f;
            }
#pragma unroll
            for (int r = 0; r < NROW; ++r) {
                unsigned lo = pk_(rv[r][0], rv[r][1]);
                unsigned hi = pk_(rv[r][2], rv[r][3]);
                *(uint2*)&TB[((esg * NROW + r) * 16 + e16) * TSTR + u0] = make_uint2(lo, hi);
            }
        }
        __syncthreads();

        // ---- MFMA phase: wave (sg, wh) ----
        f32x4 cS0 = {0,0,0,0}, cS1 = {0,0,0,0}, cG0 = {0,0,0,0}, cG1 = {0,0,0,0};
        f32x4 cV[3][2];
#pragma unroll
        for (int k = 0; k < 3; ++k) { cV[k][0] = (f32x4){0,0,0,0}; cV[k][1] = (f32x4){0,0,0,0}; }

        #define LOADA(r) ({ FragU fa_; fa_.u = *(const uint4*)&TB[((sg * NROW + (r)) * 16 + col) * TSTR + quad * 8]; fa_.v; })

        bf16x8 a0 = LOADA(0), a1 = LOADA(1);
        cS0 = mfma_(a0, Bt[0][0], cS0); cS0 = mfma_(a1, Bt[1][0], cS0);
        cS1 = mfma_(a0, Bt[0][1], cS1); cS1 = mfma_(a1, Bt[1][1], cS1);
        cG0 = mfma_(a0, Bt[2][0], cG0); cG0 = mfma_(a1, Bt[3][0], cG0);
        cG1 = mfma_(a0, Bt[2][1], cG1); cG1 = mfma_(a1, Bt[3][1], cG1);
#pragma unroll
        for (int k = 0; k < 3; ++k) {
            bf16x8 ak;
            ak = LOADA(2 + k);
            cV[k][0] = mfma_(ak, Bt[4][0], cV[k][0]);
            cV[k][1] = mfma_(ak, Bt[4][1], cV[k][1]);
            ak = LOADA(5 + k);
            cV[k][0] = mfma_(ak, Bt[5][0], cV[k][0]);
            cV[k][1] = mfma_(ak, Bt[5][1], cV[k][1]);
            ak = LOADA(8 + k);
            cV[k][0] = mfma_(ak, Bt[6][0], cV[k][0]);
            cV[k][1] = mfma_(ak, Bt[6][1], cV[k][1]);
        }

        // ---- epilogue: combine Ta + f*D, scale, store ----
        const int w = wh * 16 + col;
#pragma unroll
        for (int reg = 0; reg < 4; ++reg) {
            int e = sg * 16 + quad * 4 + reg;
            if (e < cntE) {
                float f = ECF[e];
                int eid = ECE[e];
                float* mp = msg + (size_t)eid * 160;
                mp[w]            = (cS0[reg] + f * cS1[reg]) * A0;
                mp[32 + w]       = (cG0[reg] + f * cG1[reg]) * A0;
                mp[64 + 3 * w]     = (cV[0][0][reg] + f * cV[0][1][reg]) * A1;
                mp[64 + 3 * w + 1] = (cV[1][0][reg] + f * cV[1][1][reg]) * A1;
                mp[64 + 3 * w + 2] = (cV[2][0][reg] + f * cV[2][1][reg]) * A1;
            }
        }
        #undef LOADA
        er0 = nr0; er1 = nr1; er2 = nr2; er3 = nr3;
    }
}

// ---- fused gather + node epilogue: 8 nodes per block ----
__global__ __launch_bounds__(256)
void node_kernel(const float* __restrict__ x, const float* __restrict__ Wss,
                 const float* __restrict__ Wsv, const float* __restrict__ msg,
                 const int* __restrict__ sortedD, const int* __restrict__ cntD,
                 float* __restrict__ out, int N)
{
    __shared__ float ms[8][160];
    const int tid = threadIdx.x;
    const int n0 = blockIdx.x * 8;
    const float IM = 0.1767766953f;  // 1/sqrt(32)

#pragma unroll
    for (int it = 0; it < 5; ++it) {
        int task = tid + it * 256;
        int nl = task / 160;
        int c = task - nl * 160;
        int n = n0 + nl;
        if (n < N) {
            int cd = cntD[n];
            int cc = cd < DCAP ? cd : DCAP;
            const int* sp = sortedD + n * DCAP;
            float s = 0.f;
            // 8-wide MLP: preload indices (int4), issue 8 predicated msg loads
            for (int i0 = 0; i0 < cc; i0 += 8) {
                int4 ia = *(const int4*)(sp + i0);
                int4 ib = *(const int4*)(sp + i0 + 4);
                int id[8] = { ia.x, ia.y, ia.z, ia.w, ib.x, ib.y, ib.z, ib.w };
                float p[8];
#pragma unroll
                for (int k = 0; k < 8; ++k)
                    p[k] = (i0 + k < cc) ? msg[(size_t)id[k] * 160 + c] : 0.f;
#pragma unroll
                for (int k = 0; k < 8; ++k) s += p[k];
            }
            ms[nl][c] = s / fmaxf((float)cd, 1.f);
        }
    }
    __syncthreads();

#pragma unroll
    for (int it = 0; it < 2; ++it) {
        int task = tid + it * 256;
        int nl = task >> 6, col = task & 63;
        int n = n0 + nl;
        if (n >= N) continue;
        const float* m  = ms[nl];
        const float* xp = x + (size_t)n * 128;
        if (col < 32) {
            int w = col;
            float mval = m[w];
            float gs = mval * sigmoidf_(mval);
            float dot = 0.f;
#pragma unroll 4
            for (int u = 0; u < 32; ++u) dot += xp[u] * Wss[u * 32 + w];
            float hs = gs + dot * IM;
            out[(size_t)n * 64 + w] = sqrtf(hs * hs + 1e-12f);
        } else {
            int w = col - 32;
            float gate = sigmoidf_(m[32 + w]);
            float g0 = m[64 + 3 * w + 0] * gate;
            float g1 = m[64 + 3 * w + 1] * gate;
            float g2 = m[64 + 3 * w + 2] * gate;
            float d0 = 0.f, d1 = 0.f, d2 = 0.f;
#pragma unroll 4
            for (int u = 0; u < 32; ++u) {
                float wv = Wsv[u * 32 + w];
                d0 += xp[32 + 3 * u + 0] * wv;
                d1 += xp[32 + 3 * u + 1] * wv;
                d2 += xp[32 + 3 * u + 2] * wv;
            }
            float h0 = g0 + d0 * IM, h1 = g1 + d1 * IM, h2 = g2 + d2 * IM;
            out[(size_t)n * 64 + 32 + w] = sqrtf(h0 * h0 + h1 * h1 + h2 * h2 + 1e-12f);
        }
    }
}

extern "C" void kernel_launch(void* const* d_in, const int* in_sizes, int n_in,
                              void* d_out, int out_size, void* d_ws, size_t ws_size,
                              hipStream_t stream)
{
    const float* x    = (const float*)d_in[0];
    const float* ea   = (const float*)d_in[1];
    const float* elen = (const float*)d_in[2];
    const int*   esrc = (const int*)d_in[3];
    const int*   edst = (const int*)d_in[4];
    const float* W1   = (const float*)d_in[5];
    const float* W2   = (const float*)d_in[6];
    const float* Wss  = (const float*)d_in[7];
    const float* Wsv  = (const float*)d_in[8];
    float* out = (float*)d_out;

    const int N = in_sizes[0] / 128;   // 4096
    const int E = in_sizes[2];         // 32768

    float* T      = (float*)d_ws;                       // 257*TPW floats (7.4 MB)
    float* Bpkf   = T + (size_t)257 * TPW;              // 256*28*64 uint4 (7.3 MB)
    float* msg    = Bpkf + (size_t)256 * 28 * 64 * 4;   // E*160 floats (21 MB)
    float* erec   = msg + (size_t)E * 160;              // 256*BCAP*16 floats (4 MB)
    int*   cntL   = (int*)(erec + (size_t)256 * BCAP * 16); // 256
    int*   cntD   = cntL + 256;                         // N (4096)
    int*   sortedD= cntD + N;                           // N*DCAP
    uint4* Bpk    = (uint4*)Bpkf;

    hipMemsetAsync(cntL, 0, (size_t)(256 + N) * sizeof(int), stream);

    prep_kernel<<<PREPT + (E + 255) / 256, 256, 0, stream>>>(W1, W2, elen, esrc, edst, ea, T, cntL, cntD, erec, sortedD, E);
    pack_kernel<<<NIVL, 256, 0, stream>>>(T, Bpk);
    fold_kernel<<<NIVL * 4, 256, 0, stream>>>(x, cntL, erec, Bpk, msg);
    node_kernel<<<(N + 7) / 8, 256, 0, stream>>>(x, Wss, Wsv, msg, sortedD, cntD, out, N);
}

// Round 6
// 139.910 us; speedup vs baseline: 1.1182x; 1.0652x over previous
//
#include <hip/hip_runtime.h>

#define NIVL  256
#define KINV  51.2f        // 256/5
#define KSTEP 0.01953125f  // 5/256 (exact in fp32)
#define TPW   7168
#define BCAP  256          // max edges per L-bin (avg 128)
#define DCAP  64           // max edges per dst node (avg 8)
#define NROW  11           // distinct t-rows: t00,t11,t01[3],t10[3],t12[3]
#define TSTR  40           // u-stride (pad 32->40: 80B rows -> 16B-aligned b128)
#define PREPT 455          // T-build blocks: ceil(257/4)=65 k-groups x 7 w-slices

typedef __attribute__((ext_vector_type(8))) __bf16 bf16x8;
typedef __attribute__((ext_vector_type(4))) float f32x4;
union FragU { uint4 u; bf16x8 v; };

__device__ __forceinline__ float sigmoidf_(float v) { return 1.f / (1.f + expf(-v)); }
__device__ __forceinline__ unsigned bf16r_(float x) { return (__float_as_uint(x) + 0x8000u) >> 16; }
__device__ __forceinline__ unsigned pk_(float lo, float hi) { return (bf16r_(hi) << 16) | bf16r_(lo); }

__device__ __forceinline__ f32x4 mfma_(bf16x8 a, bf16x8 b, f32x4 c) {
    return __builtin_amdgcn_mfma_f32_16x16x32_bf16(a, b, c, 0, 0, 0);
}

// ---- fat kernel: blocks 0..454 build T (257 knots, 4/block), blocks 455.. scatter ----
// Scatter bakes a 64B edge record (EREC) so fold never chases esrc/ea/elen.
__global__ __launch_bounds__(256)
void prep_kernel(const float* __restrict__ W1, const float* __restrict__ W2,
                 const float* __restrict__ elen, const int* __restrict__ esrc,
                 const int* __restrict__ edst, const float* __restrict__ ea,
                 float* __restrict__ T, int* __restrict__ cntL, int* __restrict__ cntD,
                 float* __restrict__ erec, int* __restrict__ sortedD, int E)
{
    const int tid = threadIdx.x;
    if (blockIdx.x < PREPT) {
        __shared__ float hk_s[4][64];
        const int bx = blockIdx.x % 7;
        const int k0 = (blockIdx.x / 7) * 4;
        const int pw = bx * 1024 + tid * 4;
        {
            int kk = tid >> 6, c = tid & 63;
            float L = (float)(k0 + kk) * KSTEP;
            float d = 0.f;
#pragma unroll
            for (int r = 0; r < 8; ++r) {
                float dd = L - (float)r * (5.f / 7.f);
                d += expf(-dd * dd * 0.98f) * W1[r * 64 + c];
            }
            d *= 0.3535533906f;                      // 1/sqrt(8)
            hk_s[kk][c] = d * sigmoidf_(d) * 0.125f; // silu * 1/sqrt(64)
        }
        __syncthreads();
        float4 acc[4];
#pragma unroll
        for (int q = 0; q < 4; ++q) acc[q] = make_float4(0.f, 0.f, 0.f, 0.f);
        // unroll 4: keep 4 independent W2 loads (28KB stride, L2) in flight
#pragma unroll 4
        for (int c = 0; c < 64; ++c) {
            float4 w4 = *(const float4*)(W2 + (size_t)c * TPW + pw);
#pragma unroll
            for (int q = 0; q < 4; ++q) {
                float hv = hk_s[q][c];
                acc[q].x = fmaf(hv, w4.x, acc[q].x);
                acc[q].y = fmaf(hv, w4.y, acc[q].y);
                acc[q].z = fmaf(hv, w4.z, acc[q].z);
                acc[q].w = fmaf(hv, w4.w, acc[q].w);
            }
        }
#pragma unroll
        for (int q = 0; q < 4; ++q) {
            int k = k0 + q;
            if (k < 257)
                *(float4*)(T + (size_t)k * TPW + pw) = acc[q];
        }
    } else {
        const float I3 = 0.5773502692f, I5 = 0.4472135955f, S2 = 0.7071067812f;
        const float I6 = 0.4082482905f, T6 = 0.8164965809f;
        int e = (blockIdx.x - PREPT) * 256 + tid;
        if (e < E) {
            float t = elen[e] * KINV;
            int j = (int)t; j = j > 255 ? 255 : j;
            int pos = atomicAdd(&cntL[j], 1);
            if (pos < BCAP) {
                const float* y = ea + (size_t)e * 9;
                float y0 = y[0];
                float a = y[4], b = y[5], c = y[6], d2 = y[7], ee = y[8];
                float4 r0, r1, r2, r3;
                r0.x = t - (float)j;
                r0.y = __int_as_float(esrc[e]);
                r0.z = __int_as_float(e);
                r0.w = y0;
                r1.x = y0 * I3;
                r1.y = y[1] * I3; r1.z = y[2] * I3; r1.w = y[3] * I3;
                r2.x = (-c * I6 + ee * S2) * I5;   // M0
                r2.y = a * S2 * I5;                // M1 (=M3)
                r2.z = d2 * S2 * I5;               // M2 (=M6)
                r2.w = (-c * I6 - ee * S2) * I5;   // M4
                r3.x = b * S2 * I5;                // M5 (=M7)
                r3.y = c * T6 * I5;                // M8
                r3.z = 0.f; r3.w = 0.f;
                float4* dst = (float4*)(erec + ((size_t)j * BCAP + pos) * 16);
                dst[0] = r0; dst[1] = r1; dst[2] = r2; dst[3] = r3;
            }
            int d = edst[e];
            int pd = atomicAdd(&cntD[d], 1);
            if (pd < DCAP) sortedD[d * DCAP + pd] = e;
        }
    }
}

// ---- pack kernel: T -> per-lane bf16 fragment layout, once per interval ----
// Bpk[(j*28 + pl*4 + tad*2 + wh)*64 + lane] (uint4). Replicates the exact
// staging arithmetic so fold consumes identical bits.
__global__ __launch_bounds__(256)
void pack_kernel(const float* __restrict__ T, uint4* __restrict__ Bpk)
{
    const int j = blockIdx.x;
    const int tid = threadIdx.x;
    const float* Trow  = T + (size_t)j * TPW;
    const float* Trow2 = Trow + TPW;
    uint4* bp = Bpk + (size_t)j * 28 * 64;
    for (int i = tid; i < 896; i += 256) {
        int pl = i >> 7, rem = i & 127;
        int whs = rem >> 6, lane_s = rem & 63;
        int u0 = (lane_s >> 4) * 8, w = whs * 16 + (lane_s & 15);
        int basei = pl * 1024 + w;
        unsigned ta[4], dd[4];
#pragma unroll
        for (int q = 0; q < 4; ++q) {
            float a0 = Trow[basei + (u0 + 2 * q) * 32];
            float a1 = Trow[basei + (u0 + 2 * q + 1) * 32];
            float b0 = Trow2[basei + (u0 + 2 * q) * 32];
            float b1 = Trow2[basei + (u0 + 2 * q + 1) * 32];
            ta[q] = pk_(a0, a1);
            dd[q] = pk_(b0 - a0, b1 - a1);
        }
        bp[(pl * 4 + whs) * 64 + lane_s]     = make_uint4(ta[0], ta[1], ta[2], ta[3]);
        bp[(pl * 4 + 2 + whs) * 64 + lane_s] = make_uint4(dd[0], dd[1], dd[2], dd[3]);
    }
}

// ---- main fold: MFMA formulation, B-fragments in registers from packed global ----
// 2 blocks per interval (half-strided chunks, avg 2 chunks/block). Prologue:
// each lane does 14 coalesced b128 loads of its own fragments (no BF LDS, no
// staging barriers, no LOADB ds_reads in MFMA phase). launch_bounds(256,2) ->
// VGPR cap 256, no spill (~190 live). LDS = TB only (28.2KB). Per chunk: erec
// prefetched one ahead; x-row load before barrier; t-build 11 rows/edge;
// 26 MFMAs/wave with register B-operands; epilogue Ta + f*D -> msg.
__global__ __launch_bounds__(256, 2)
void fold_kernel(const float* __restrict__ x, const int* __restrict__ cntL,
                 const float* __restrict__ erec, const uint4* __restrict__ Bpk,
                 float* __restrict__ msg)
{
    const int j = blockIdx.x >> 1, half = blockIdx.x & 1;
    __shared__ __align__(16) unsigned short TB[2 * NROW * 16 * TSTR]; // 28160 B
    __shared__ float ECF[32];
    __shared__ int   ECE[32];
    const int tid = threadIdx.x;

    const int cnt = min(cntL[j], BCAP);
    const int nchunk = (cnt + 31) >> 5;
    const int te = tid & 31, sub = tid >> 5;     // t-build mapping
    const int wv = tid >> 6, lane = tid & 63;
    const int sg = wv >> 1, wh = wv & 1;
    const int col = lane & 15, quad = lane >> 4;

    // ---- prologue: load edge record for first chunk (overlaps B-frag loads) ----
    float4 er0 = {0,0,0,0}, er1 = {0,0,0,0}, er2 = {0,0,0,0}, er3 = {0,0,0,0};
    if (half < nchunk) {
        int ce = min(32, cnt - (half << 5));
        if (te < ce) {
            const float4* rp = (const float4*)(erec + ((size_t)j * BCAP + (half << 5) + te) * 16);
            er0 = rp[0]; er1 = rp[1]; er2 = rp[2]; er3 = rp[3];
        }
    }

    // ---- B-fragments: 14 coalesced b128 loads (loop-invariant) ----
    bf16x8 Bt[7][2];
    {
        const uint4* bp = Bpk + (size_t)j * 28 * 64 + lane;
#pragma unroll
        for (int pl = 0; pl < 7; ++pl) {
            FragU fa; fa.u = bp[(pl * 4 + wh) * 64];     Bt[pl][0] = fa.v;
            FragU fd; fd.u = bp[(pl * 4 + 2 + wh) * 64]; Bt[pl][1] = fd.v;
        }
    }

    const float A0 = 0.125f, A1 = 0.1767766953f;

    for (int ci = half; ci < nchunk; ci += 2) {
        const int base = ci << 5;
        const int cntE = min(32, cnt - base);

        // ---- x-row load for current chunk (record already in regs) ----
        const int u0 = sub * 4;
        float s4[4], vv[12];
        if (te < cntE) {
            int src = __float_as_int(er0.y);
            const float* xp = x + (size_t)src * 128;
            *(float4*)s4 = *(const float4*)(xp + u0);
            *(float4*)(vv)     = *(const float4*)(xp + 32 + 3 * u0);
            *(float4*)(vv + 4) = *(const float4*)(xp + 32 + 3 * u0 + 4);
            *(float4*)(vv + 8) = *(const float4*)(xp + 32 + 3 * u0 + 8);
        }
        // ---- prefetch next chunk's record ----
        float4 nr0 = {0,0,0,0}, nr1 = {0,0,0,0}, nr2 = {0,0,0,0}, nr3 = {0,0,0,0};
        const int cin = ci + 2;
        if (cin < nchunk) {
            int ce2 = min(32, cnt - (cin << 5));
            if (te < ce2) {
                const float4* rp = (const float4*)(erec + ((size_t)j * BCAP + (cin << 5) + te) * 16);
                nr0 = rp[0]; nr1 = rp[1]; nr2 = rp[2]; nr3 = rp[3];
            }
        }

        __syncthreads();   // TB/ECF/ECE free (prior iter consumed)

        // ---- t-build: thread (te, sub) computes rows for edge te, u0..u0+3 ----
        {
            const int esg = te >> 4, e16 = te & 15;
            float rv[NROW][4];
            if (te < cntE) {
                float y0 = er0.w;
                float y0i = er1.x, y1i0 = er1.y, y1i1 = er1.z, y1i2 = er1.w;
                float M0 = er2.x, M1 = er2.y, M2 = er2.z, M4 = er2.w;
                float M5 = er3.x, M8 = er3.y;
                if (sub == 0) {
                    ECF[te] = er0.x;
                    ECE[te] = __float_as_int(er0.z);   // edge id
                }
#pragma unroll
                for (int up = 0; up < 4; ++up) {
                    float s = s4[up];
                    float v0 = vv[3 * up], v1 = vv[3 * up + 1], v2 = vv[3 * up + 2];
                    rv[0][up] = s * y0;
                    rv[1][up] = v0 * y1i0 + v1 * y1i1 + v2 * y1i2;
                    rv[2][up] = s * y1i0;
                    rv[3][up] = s * y1i1;
                    rv[4][up] = s * y1i2;
                    rv[5][up] = v0 * y0i;
                    rv[6][up] = v1 * y0i;
                    rv[7][up] = v2 * y0i;
                    rv[8][up]  = v0 * M0 + v1 * M1 + v2 * M2;
                    rv[9][up]  = v0 * M1 + v1 * M4 + v2 * M5;
                    rv[10][up] = v0 * M2 + v1 * M5 + v2 * M8;
                }
            } else {
#pragma unroll
                for (int r = 0; r < NROW; ++r)
#pragma unroll
                    for (int up = 0; up < 4; ++up) rv[r][up] = 0.f;
            }
#pragma unroll
            for (int r = 0; r < NROW; ++r) {
                unsigned lo = pk_(rv[r][0], rv[r][1]);
                unsigned hi = pk_(rv[r][2], rv[r][3]);
                *(uint2*)&TB[((esg * NROW + r) * 16 + e16) * TSTR + u0] = make_uint2(lo, hi);
            }
        }
        __syncthreads();

        // ---- MFMA phase: wave (sg, wh), B-operands in registers ----
        f32x4 cS0 = {0,0,0,0}, cS1 = {0,0,0,0}, cG0 = {0,0,0,0}, cG1 = {0,0,0,0};
        f32x4 cV[3][2];
#pragma unroll
        for (int k = 0; k < 3; ++k) { cV[k][0] = (f32x4){0,0,0,0}; cV[k][1] = (f32x4){0,0,0,0}; }

        #define LOADA(r) ({ FragU fa_; fa_.u = *(const uint4*)&TB[((sg * NROW + (r)) * 16 + col) * TSTR + quad * 8]; fa_.v; })

        bf16x8 a0 = LOADA(0), a1 = LOADA(1);
        cS0 = mfma_(a0, Bt[0][0], cS0); cS0 = mfma_(a1, Bt[1][0], cS0);
        cS1 = mfma_(a0, Bt[0][1], cS1); cS1 = mfma_(a1, Bt[1][1], cS1);
        cG0 = mfma_(a0, Bt[2][0], cG0); cG0 = mfma_(a1, Bt[3][0], cG0);
        cG1 = mfma_(a0, Bt[2][1], cG1); cG1 = mfma_(a1, Bt[3][1], cG1);
#pragma unroll
        for (int k = 0; k < 3; ++k) {
            bf16x8 ak;
            ak = LOADA(2 + k);
            cV[k][0] = mfma_(ak, Bt[4][0], cV[k][0]);
            cV[k][1] = mfma_(ak, Bt[4][1], cV[k][1]);
            ak = LOADA(5 + k);
            cV[k][0] = mfma_(ak, Bt[5][0], cV[k][0]);
            cV[k][1] = mfma_(ak, Bt[5][1], cV[k][1]);
            ak = LOADA(8 + k);
            cV[k][0] = mfma_(ak, Bt[6][0], cV[k][0]);
            cV[k][1] = mfma_(ak, Bt[6][1], cV[k][1]);
        }

        // ---- epilogue: combine Ta + f*D, scale, store ----
        const int w = wh * 16 + col;
#pragma unroll
        for (int reg = 0; reg < 4; ++reg) {
            int e = sg * 16 + quad * 4 + reg;
            if (e < cntE) {
                float f = ECF[e];
                int eid = ECE[e];
                float* mp = msg + (size_t)eid * 160;
                mp[w]            = (cS0[reg] + f * cS1[reg]) * A0;
                mp[32 + w]       = (cG0[reg] + f * cG1[reg]) * A0;
                mp[64 + 3 * w]     = (cV[0][0][reg] + f * cV[0][1][reg]) * A1;
                mp[64 + 3 * w + 1] = (cV[1][0][reg] + f * cV[1][1][reg]) * A1;
                mp[64 + 3 * w + 2] = (cV[2][0][reg] + f * cV[2][1][reg]) * A1;
            }
        }
        #undef LOADA
        er0 = nr0; er1 = nr1; er2 = nr2; er3 = nr3;
    }
}

// ---- fused gather + node epilogue: 8 nodes per block ----
__global__ __launch_bounds__(256)
void node_kernel(const float* __restrict__ x, const float* __restrict__ Wss,
                 const float* __restrict__ Wsv, const float* __restrict__ msg,
                 const int* __restrict__ sortedD, const int* __restrict__ cntD,
                 float* __restrict__ out, int N)
{
    __shared__ float ms[8][160];
    const int tid = threadIdx.x;
    const int n0 = blockIdx.x * 8;
    const float IM = 0.1767766953f;  // 1/sqrt(32)

#pragma unroll
    for (int it = 0; it < 5; ++it) {
        int task = tid + it * 256;
        int nl = task / 160;
        int c = task - nl * 160;
        int n = n0 + nl;
        if (n < N) {
            int cd = cntD[n];
            int cc = cd < DCAP ? cd : DCAP;
            const int* sp = sortedD + n * DCAP;
            float s = 0.f;
            // 8-wide MLP: preload indices (int4), issue 8 predicated msg loads
            for (int i0 = 0; i0 < cc; i0 += 8) {
                int4 ia = *(const int4*)(sp + i0);
                int4 ib = *(const int4*)(sp + i0 + 4);
                int id[8] = { ia.x, ia.y, ia.z, ia.w, ib.x, ib.y, ib.z, ib.w };
                float p[8];
#pragma unroll
                for (int k = 0; k < 8; ++k)
                    p[k] = (i0 + k < cc) ? msg[(size_t)id[k] * 160 + c] : 0.f;
#pragma unroll
                for (int k = 0; k < 8; ++k) s += p[k];
            }
            ms[nl][c] = s / fmaxf((float)cd, 1.f);
        }
    }
    __syncthreads();

#pragma unroll
    for (int it = 0; it < 2; ++it) {
        int task = tid + it * 256;
        int nl = task >> 6, col = task & 63;
        int n = n0 + nl;
        if (n >= N) continue;
        const float* m  = ms[nl];
        const float* xp = x + (size_t)n * 128;
        if (col < 32) {
            int w = col;
            float mval = m[w];
            float gs = mval * sigmoidf_(mval);
            float dot = 0.f;
#pragma unroll 4
            for (int u = 0; u < 32; ++u) dot += xp[u] * Wss[u * 32 + w];
            float hs = gs + dot * IM;
            out[(size_t)n * 64 + w] = sqrtf(hs * hs + 1e-12f);
        } else {
            int w = col - 32;
            float gate = sigmoidf_(m[32 + w]);
            float g0 = m[64 + 3 * w + 0] * gate;
            float g1 = m[64 + 3 * w + 1] * gate;
            float g2 = m[64 + 3 * w + 2] * gate;
            float d0 = 0.f, d1 = 0.f, d2 = 0.f;
#pragma unroll 4
            for (int u = 0; u < 32; ++u) {
                float wv = Wsv[u * 32 + w];
                d0 += xp[32 + 3 * u + 0] * wv;
                d1 += xp[32 + 3 * u + 1] * wv;
                d2 += xp[32 + 3 * u + 2] * wv;
            }
            float h0 = g0 + d0 * IM, h1 = g1 + d1 * IM, h2 = g2 + d2 * IM;
            out[(size_t)n * 64 + 32 + w] = sqrtf(h0 * h0 + h1 * h1 + h2 * h2 + 1e-12f);
        }
    }
}

extern "C" void kernel_launch(void* const* d_in, const int* in_sizes, int n_in,
                              void* d_out, int out_size, void* d_ws, size_t ws_size,
                              hipStream_t stream)
{
    const float* x    = (const float*)d_in[0];
    const float* ea   = (const float*)d_in[1];
    const float* elen = (const float*)d_in[2];
    const int*   esrc = (const int*)d_in[3];
    const int*   edst = (const int*)d_in[4];
    const float* W1   = (const float*)d_in[5];
    const float* W2   = (const float*)d_in[6];
    const float* Wss  = (const float*)d_in[7];
    const float* Wsv  = (const float*)d_in[8];
    float* out = (float*)d_out;

    const int N = in_sizes[0] / 128;   // 4096
    const int E = in_sizes[2];         // 32768

    float* T      = (float*)d_ws;                       // 257*TPW floats (7.4 MB)
    float* Bpkf   = T + (size_t)257 * TPW;              // 256*28*64 uint4 (7.3 MB)
    float* msg    = Bpkf + (size_t)256 * 28 * 64 * 4;   // E*160 floats (21 MB)
    float* erec   = msg + (size_t)E * 160;              // 256*BCAP*16 floats (4 MB)
    int*   cntL   = (int*)(erec + (size_t)256 * BCAP * 16); // 256
    int*   cntD   = cntL + 256;                         // N (4096)
    int*   sortedD= cntD + N;                           // N*DCAP
    uint4* Bpk    = (uint4*)Bpkf;

    hipMemsetAsync(cntL, 0, (size_t)(256 + N) * sizeof(int), stream);

    prep_kernel<<<PREPT + (E + 255) / 256, 256, 0, stream>>>(W1, W2, elen, esrc, edst, ea, T, cntL, cntD, erec, sortedD, E);
    pack_kernel<<<NIVL, 256, 0, stream>>>(T, Bpk);
    fold_kernel<<<NIVL * 2, 256, 0, stream>>>(x, cntL, erec, Bpk, msg);
    node_kernel<<<(N + 7) / 8, 256, 0, stream>>>(x, Wss, Wsv, msg, sortedD, cntD, out, N);
}

// Round 8
// 134.741 us; speedup vs baseline: 1.1611x; 1.0384x over previous
//
#include <hip/hip_runtime.h>

#define NIVL  256
#define KINV  51.2f        // 256/5
#define KSTEP 0.01953125f  // 5/256 (exact in fp32)
#define TPW   7168
#define BCAP  256          // max edges per L-bin (avg 128)
#define DCAP  64           // max edges per dst node (avg 8)
#define NROW  11           // distinct t-rows: t00,t11,t01[3],t10[3],t12[3]
#define TSTR  40           // u-stride (pad 32->40: 80B rows -> 16B-aligned b128)
#define TPACK 448          // T-build+pack blocks: 64 k-groups x 7 w-slices

typedef __attribute__((ext_vector_type(8))) __bf16 bf16x8;
typedef __attribute__((ext_vector_type(4))) float f32x4;
union FragU { uint4 u; bf16x8 v; };

__device__ __forceinline__ float sigmoidf_(float v) { return 1.f / (1.f + expf(-v)); }
__device__ __forceinline__ unsigned bf16r_(float x) { return (__float_as_uint(x) + 0x8000u) >> 16; }
__device__ __forceinline__ unsigned pk_(float lo, float hi) { return (bf16r_(hi) << 16) | bf16r_(lo); }

__device__ __forceinline__ f32x4 mfma_(bf16x8 a, bf16x8 b, f32x4 c) {
    return __builtin_amdgcn_mfma_f32_16x16x32_bf16(a, b, c, 0, 0, 0);
}

// ---- prep: blocks 0..447 fused T-build(5 knots in LDS)+pack -> Bpk;
//      blocks 448.. edge scatter -> erec/cntL/cntD/sortedD(slots).
// T never touches global memory; pack launch eliminated.
__global__ __launch_bounds__(256)
void prep_kernel(const float* __restrict__ W1, const float* __restrict__ W2,
                 const float* __restrict__ elen, const int* __restrict__ esrc,
                 const int* __restrict__ edst, const float* __restrict__ ea,
                 uint4* __restrict__ Bpk, int* __restrict__ cntL, int* __restrict__ cntD,
                 float* __restrict__ erec, int* __restrict__ sortedD, int E)
{
    __shared__ float hk_s[5][64];
    __shared__ float Tsl[5][1024];
    const int tid = threadIdx.x;
    const int vb = blockIdx.x;
    if (vb < TPACK) {
        const int bx = vb % 7;            // W2 slice (1024 cols)
        const int k0 = (vb / 7) * 4;      // first interval of this group
        // radial MLP hidden layer for 5 knots (k0..k0+4)
        for (int idx = tid; idx < 320; idx += 256) {
            int kk = idx >> 6, c = idx & 63;
            float L = (float)(k0 + kk) * KSTEP;
            float d = 0.f;
#pragma unroll
            for (int r = 0; r < 8; ++r) {
                float dd = L - (float)r * (5.f / 7.f);
                d += expf(-dd * dd * 0.98f) * W1[r * 64 + c];
            }
            d *= 0.3535533906f;                      // 1/sqrt(8)
            hk_s[kk][c] = d * sigmoidf_(d) * 0.125f; // silu * 1/sqrt(64)
        }
        __syncthreads();
        // second layer: 5 knots x 4 cols per thread
        float4 acc[5];
#pragma unroll
        for (int q = 0; q < 5; ++q) acc[q] = make_float4(0.f, 0.f, 0.f, 0.f);
        const int pw = bx * 1024 + tid * 4;
#pragma unroll 4
        for (int c = 0; c < 64; ++c) {
            float4 w4 = *(const float4*)(W2 + (size_t)c * TPW + pw);
#pragma unroll
            for (int q = 0; q < 5; ++q) {
                float hv = hk_s[q][c];
                acc[q].x = fmaf(hv, w4.x, acc[q].x);
                acc[q].y = fmaf(hv, w4.y, acc[q].y);
                acc[q].z = fmaf(hv, w4.z, acc[q].z);
                acc[q].w = fmaf(hv, w4.w, acc[q].w);
            }
        }
        __syncthreads();
#pragma unroll
        for (int q = 0; q < 5; ++q)
            *(float4*)&Tsl[q][tid * 4] = acc[q];
        __syncthreads();
        // pack 4 intervals of this slice directly from LDS
        const int lane_s = tid & 63, whs = (tid >> 6) & 1, ih = tid >> 7;
        const int u0p = (lane_s >> 4) * 8, wp = whs * 16 + (lane_s & 15);
#pragma unroll
        for (int t2 = 0; t2 < 2; ++t2) {
            const int jj = k0 + ih + t2 * 2;   // interval
            const int kk = jj - k0;            // local knot
            unsigned ta[4], dd[4];
#pragma unroll
            for (int q = 0; q < 4; ++q) {
                float a0 = Tsl[kk][(u0p + 2 * q) * 32 + wp];
                float a1 = Tsl[kk][(u0p + 2 * q + 1) * 32 + wp];
                float b0 = Tsl[kk + 1][(u0p + 2 * q) * 32 + wp];
                float b1 = Tsl[kk + 1][(u0p + 2 * q + 1) * 32 + wp];
                ta[q] = pk_(a0, a1);
                dd[q] = pk_(b0 - a0, b1 - a1);
            }
            Bpk[((size_t)jj * 28 + bx * 4 + whs) * 64 + lane_s]     = make_uint4(ta[0], ta[1], ta[2], ta[3]);
            Bpk[((size_t)jj * 28 + bx * 4 + 2 + whs) * 64 + lane_s] = make_uint4(dd[0], dd[1], dd[2], dd[3]);
        }
    } else {
        const float I3 = 0.5773502692f, I5 = 0.4472135955f, S2 = 0.7071067812f;
        const float I6 = 0.4082482905f, T6 = 0.8164965809f;
        int e = (vb - TPACK) * 256 + tid;
        if (e < E) {
            float t = elen[e] * KINV;
            int j = (int)t; j = j > 255 ? 255 : j;
            int pos = atomicAdd(&cntL[j], 1);
            if (pos < BCAP) {
                const float* y = ea + (size_t)e * 9;
                float y0 = y[0];
                float a = y[4], b = y[5], c = y[6], d2 = y[7], ee = y[8];
                float4 r0, r1, r2, r3;
                r0.x = t - (float)j;
                r0.y = __int_as_float(esrc[e]);
                r0.z = 0.f;                        // (unused; fold derives slot)
                r0.w = y0;
                r1.x = y0 * I3;
                r1.y = y[1] * I3; r1.z = y[2] * I3; r1.w = y[3] * I3;
                r2.x = (-c * I6 + ee * S2) * I5;   // M0
                r2.y = a * S2 * I5;                // M1 (=M3)
                r2.z = d2 * S2 * I5;               // M2 (=M6)
                r2.w = (-c * I6 - ee * S2) * I5;   // M4
                r3.x = b * S2 * I5;                // M5 (=M7)
                r3.y = c * T6 * I5;                // M8
                r3.z = 0.f; r3.w = 0.f;
                float4* dst = (float4*)(erec + ((size_t)j * BCAP + pos) * 16);
                dst[0] = r0; dst[1] = r1; dst[2] = r2; dst[3] = r3;
            }
            // msg is slot-indexed: sortedD stores the bin slot (clamped in-bounds)
            int slot = j * BCAP + (pos < BCAP ? pos : BCAP - 1);
            int d = edst[e];
            int pd = atomicAdd(&cntD[d], 1);
            if (pd < DCAP) sortedD[d * DCAP + pd] = slot;
        }
    }
}

// ---- main fold: MFMA, register B-frags from Bpk, slot-indexed msg stores ----
// 2 blocks per interval (half-strided chunks). msg rows for a chunk's 32 edges
// are contiguous (slot = j*BCAP+base+e) -> block collectively covers full
// cachelines -> no partial-line HBM writes. LDS = TB only; LB(256,2).
__global__ __launch_bounds__(256, 2)
void fold_kernel(const float* __restrict__ x, const int* __restrict__ cntL,
                 const float* __restrict__ erec, const uint4* __restrict__ Bpk,
                 float* __restrict__ msg)
{
    const int j = blockIdx.x >> 1, half = blockIdx.x & 1;
    __shared__ __align__(16) unsigned short TB[2 * NROW * 16 * TSTR]; // 28160 B
    __shared__ float ECF[32];
    const int tid = threadIdx.x;

    const int cnt = min(cntL[j], BCAP);
    const int nchunk = (cnt + 31) >> 5;
    const int te = tid & 31, sub = tid >> 5;
    const int wv = tid >> 6, lane = tid & 63;
    const int sg = wv >> 1, wh = wv & 1;
    const int col = lane & 15, quad = lane >> 4;

    // prologue: first chunk's edge record
    float4 er0 = {0,0,0,0}, er1 = {0,0,0,0}, er2 = {0,0,0,0}, er3 = {0,0,0,0};
    if (half < nchunk) {
        int ce = min(32, cnt - (half << 5));
        if (te < ce) {
            const float4* rp = (const float4*)(erec + ((size_t)j * BCAP + (half << 5) + te) * 16);
            er0 = rp[0]; er1 = rp[1]; er2 = rp[2]; er3 = rp[3];
        }
    }

    // B-fragments: 14 coalesced b128 loads (loop-invariant)
    bf16x8 Bt[7][2];
    {
        const uint4* bp = Bpk + (size_t)j * 28 * 64 + lane;
#pragma unroll
        for (int pl = 0; pl < 7; ++pl) {
            FragU fa; fa.u = bp[(pl * 4 + wh) * 64];     Bt[pl][0] = fa.v;
            FragU fd; fd.u = bp[(pl * 4 + 2 + wh) * 64]; Bt[pl][1] = fd.v;
        }
    }

    const float A0 = 0.125f, A1 = 0.1767766953f;

    for (int ci = half; ci < nchunk; ci += 2) {
        const int base = ci << 5;
        const int cntE = min(32, cnt - base);

        const int u0 = sub * 4;
        float s4[4], vvx[12];
        if (te < cntE) {
            int src = __float_as_int(er0.y);
            const float* xp = x + (size_t)src * 128;
            *(float4*)s4 = *(const float4*)(xp + u0);
            *(float4*)(vvx)     = *(const float4*)(xp + 32 + 3 * u0);
            *(float4*)(vvx + 4) = *(const float4*)(xp + 32 + 3 * u0 + 4);
            *(float4*)(vvx + 8) = *(const float4*)(xp + 32 + 3 * u0 + 8);
        }
        float4 nr0 = {0,0,0,0}, nr1 = {0,0,0,0}, nr2 = {0,0,0,0}, nr3 = {0,0,0,0};
        const int cin = ci + 2;
        if (cin < nchunk) {
            int ce2 = min(32, cnt - (cin << 5));
            if (te < ce2) {
                const float4* rp = (const float4*)(erec + ((size_t)j * BCAP + (cin << 5) + te) * 16);
                nr0 = rp[0]; nr1 = rp[1]; nr2 = rp[2]; nr3 = rp[3];
            }
        }

        __syncthreads();

        {
            const int esg = te >> 4, e16 = te & 15;
            float rv[NROW][4];
            if (te < cntE) {
                float y0 = er0.w;
                float y0i = er1.x, y1i0 = er1.y, y1i1 = er1.z, y1i2 = er1.w;
                float M0 = er2.x, M1 = er2.y, M2 = er2.z, M4 = er2.w;
                float M5 = er3.x, M8 = er3.y;
                if (sub == 0) ECF[te] = er0.x;
#pragma unroll
                for (int up = 0; up < 4; ++up) {
                    float s = s4[up];
                    float v0 = vvx[3 * up], v1 = vvx[3 * up + 1], v2 = vvx[3 * up + 2];
                    rv[0][up] = s * y0;
                    rv[1][up] = v0 * y1i0 + v1 * y1i1 + v2 * y1i2;
                    rv[2][up] = s * y1i0;
                    rv[3][up] = s * y1i1;
                    rv[4][up] = s * y1i2;
                    rv[5][up] = v0 * y0i;
                    rv[6][up] = v1 * y0i;
                    rv[7][up] = v2 * y0i;
                    rv[8][up]  = v0 * M0 + v1 * M1 + v2 * M2;
                    rv[9][up]  = v0 * M1 + v1 * M4 + v2 * M5;
                    rv[10][up] = v0 * M2 + v1 * M5 + v2 * M8;
                }
            } else {
#pragma unroll
                for (int r = 0; r < NROW; ++r)
#pragma unroll
                    for (int up = 0; up < 4; ++up) rv[r][up] = 0.f;
            }
#pragma unroll
            for (int r = 0; r < NROW; ++r) {
                unsigned lo = pk_(rv[r][0], rv[r][1]);
                unsigned hi = pk_(rv[r][2], rv[r][3]);
                *(uint2*)&TB[((esg * NROW + r) * 16 + e16) * TSTR + u0] = make_uint2(lo, hi);
            }
        }
        __syncthreads();

        f32x4 cS0 = {0,0,0,0}, cS1 = {0,0,0,0}, cG0 = {0,0,0,0}, cG1 = {0,0,0,0};
        f32x4 cV[3][2];
#pragma unroll
        for (int k = 0; k < 3; ++k) { cV[k][0] = (f32x4){0,0,0,0}; cV[k][1] = (f32x4){0,0,0,0}; }

        #define LOADA(r) ({ FragU fa_; fa_.u = *(const uint4*)&TB[((sg * NROW + (r)) * 16 + col) * TSTR + quad * 8]; fa_.v; })

        bf16x8 a0 = LOADA(0), a1 = LOADA(1);
        cS0 = mfma_(a0, Bt[0][0], cS0); cS0 = mfma_(a1, Bt[1][0], cS0);
        cS1 = mfma_(a0, Bt[0][1], cS1); cS1 = mfma_(a1, Bt[1][1], cS1);
        cG0 = mfma_(a0, Bt[2][0], cG0); cG0 = mfma_(a1, Bt[3][0], cG0);
        cG1 = mfma_(a0, Bt[2][1], cG1); cG1 = mfma_(a1, Bt[3][1], cG1);
#pragma unroll
        for (int k = 0; k < 3; ++k) {
            bf16x8 ak;
            ak = LOADA(2 + k);
            cV[k][0] = mfma_(ak, Bt[4][0], cV[k][0]);
            cV[k][1] = mfma_(ak, Bt[4][1], cV[k][1]);
            ak = LOADA(5 + k);
            cV[k][0] = mfma_(ak, Bt[5][0], cV[k][0]);
            cV[k][1] = mfma_(ak, Bt[5][1], cV[k][1]);
            ak = LOADA(8 + k);
            cV[k][0] = mfma_(ak, Bt[6][0], cV[k][0]);
            cV[k][1] = mfma_(ak, Bt[6][1], cV[k][1]);
        }

        // epilogue: combine Ta + f*D, scale, store to slot-contiguous msg rows
        const int w = wh * 16 + col;
        const int sbase = j * BCAP + base;
#pragma unroll
        for (int reg = 0; reg < 4; ++reg) {
            int e = sg * 16 + quad * 4 + reg;
            if (e < cntE) {
                float f = ECF[e];
                float* mp = msg + (size_t)(sbase + e) * 160;
                mp[w]            = (cS0[reg] + f * cS1[reg]) * A0;
                mp[32 + w]       = (cG0[reg] + f * cG1[reg]) * A0;
                mp[64 + 3 * w]     = (cV[0][0][reg] + f * cV[0][1][reg]) * A1;
                mp[64 + 3 * w + 1] = (cV[1][0][reg] + f * cV[1][1][reg]) * A1;
                mp[64 + 3 * w + 2] = (cV[2][0][reg] + f * cV[2][1][reg]) * A1;
            }
        }
        #undef LOADA
        er0 = nr0; er1 = nr1; er2 = nr2; er3 = nr3;
    }
}

// ---- fused gather + node epilogue: 8 nodes per block (sortedD holds slots) ----
__global__ __launch_bounds__(256)
void node_kernel(const float* __restrict__ x, const float* __restrict__ Wss,
                 const float* __restrict__ Wsv, const float* __restrict__ msg,
                 const int* __restrict__ sortedD, const int* __restrict__ cntD,
                 float* __restrict__ out, int N)
{
    __shared__ float ms[8][160];
    const int tid = threadIdx.x;
    const int n0 = blockIdx.x * 8;
    const float IM = 0.1767766953f;  // 1/sqrt(32)

#pragma unroll
    for (int it = 0; it < 5; ++it) {
        int task = tid + it * 256;
        int nl = task / 160;
        int c = task - nl * 160;
        int n = n0 + nl;
        if (n < N) {
            int cd = cntD[n];
            int cc = cd < DCAP ? cd : DCAP;
            const int* sp = sortedD + n * DCAP;
            float s = 0.f;
            for (int i0 = 0; i0 < cc; i0 += 8) {
                int4 ia = *(const int4*)(sp + i0);
                int4 ib = *(const int4*)(sp + i0 + 4);
                int id[8] = { ia.x, ia.y, ia.z, ia.w, ib.x, ib.y, ib.z, ib.w };
                float p[8];
#pragma unroll
                for (int k = 0; k < 8; ++k)
                    p[k] = (i0 + k < cc) ? msg[(size_t)id[k] * 160 + c] : 0.f;
#pragma unroll
                for (int k = 0; k < 8; ++k) s += p[k];
            }
            ms[nl][c] = s / fmaxf((float)cd, 1.f);
        }
    }
    __syncthreads();

#pragma unroll
    for (int it = 0; it < 2; ++it) {
        int task = tid + it * 256;
        int nl = task >> 6, col = task & 63;
        int n = n0 + nl;
        if (n >= N) continue;
        const float* m  = ms[nl];
        const float* xp = x + (size_t)n * 128;
        if (col < 32) {
            int w = col;
            float mval = m[w];
            float gs = mval * sigmoidf_(mval);
            float dot = 0.f;
#pragma unroll 4
            for (int u = 0; u < 32; ++u) dot += xp[u] * Wss[u * 32 + w];
            float hs = gs + dot * IM;
            out[(size_t)n * 64 + w] = sqrtf(hs * hs + 1e-12f);
        } else {
            int w = col - 32;
            float gate = sigmoidf_(m[32 + w]);
            float g0 = m[64 + 3 * w + 0] * gate;
            float g1 = m[64 + 3 * w + 1] * gate;
            float g2 = m[64 + 3 * w + 2] * gate;
            float d0 = 0.f, d1 = 0.f, d2 = 0.f;
#pragma unroll 4
            for (int u = 0; u < 32; ++u) {
                float wvv = Wsv[u * 32 + w];
                d0 += xp[32 + 3 * u + 0] * wvv;
                d1 += xp[32 + 3 * u + 1] * wvv;
                d2 += xp[32 + 3 * u + 2] * wvv;
            }
            float h0 = g0 + d0 * IM, h1 = g1 + d1 * IM, h2 = g2 + d2 * IM;
            out[(size_t)n * 64 + 32 + w] = sqrtf(h0 * h0 + h1 * h1 + h2 * h2 + 1e-12f);
        }
    }
}

extern "C" void kernel_launch(void* const* d_in, const int* in_sizes, int n_in,
                              void* d_out, int out_size, void* d_ws, size_t ws_size,
                              hipStream_t stream)
{
    const float* x    = (const float*)d_in[0];
    const float* ea   = (const float*)d_in[1];
    const float* elen = (const float*)d_in[2];
    const int*   esrc = (const int*)d_in[3];
    const int*   edst = (const int*)d_in[4];
    const float* W1   = (const float*)d_in[5];
    const float* W2   = (const float*)d_in[6];
    const float* Wss  = (const float*)d_in[7];
    const float* Wsv  = (const float*)d_in[8];
    float* out = (float*)d_out;

    const int N = in_sizes[0] / 128;   // 4096
    const int E = in_sizes[2];         // 32768

    float* Bpkf   = (float*)d_ws;                       // 256*28*64 uint4 (7.3 MB)
    float* msg    = Bpkf + (size_t)256 * 28 * 64 * 4;   // 256*BCAP*160 floats (42 MB, slot-indexed)
    float* erec   = msg + (size_t)256 * BCAP * 160;     // 256*BCAP*16 floats (4 MB)
    int*   cntL   = (int*)(erec + (size_t)256 * BCAP * 16); // 256
    int*   cntD   = cntL + 256;                         // N (4096)
    int*   sortedD= cntD + N;                           // N*DCAP
    uint4* Bpk    = (uint4*)Bpkf;

    hipMemsetAsync(cntL, 0, (size_t)(256 + N) * sizeof(int), stream);

    prep_kernel<<<TPACK + (E + 255) / 256, 256, 0, stream>>>(W1, W2, elen, esrc, edst, ea, Bpk, cntL, cntD, erec, sortedD, E);
    fold_kernel<<<NIVL * 2, 256, 0, stream>>>(x, cntL, erec, Bpk, msg);
    node_kernel<<<(N + 7) / 8, 256, 0, stream>>>(x, Wss, Wsv, msg, sortedD, cntD, out, N);
}